// Round 5
// baseline (344.313 us; speedup 1.0000x reference)
//
#include <hip/hip_runtime.h>
#include <hip/hip_bf16.h>
#include <math.h>
#include <stdint.h>

#define T_TOK 8192      // b*l
#define L_SEQ 4096
#define DM    1024
#define DIN   2048
#define DSTATE 128
#define NH    32
#define HD    64
#define CH    64        // chunk length
#define NCH   64        // chunks per batch
#define NBC   128       // B * NCH
#define CONVD 2304
#define NPROJ 2336      // columns of in_proj we actually need (z gate unused)
#define NPAD  2432      // NPROJ padded to multiple of 128
#define PROJ_OFF 2048
#define DPROJ 4384

typedef __bf16 bf16x8 __attribute__((ext_vector_type(8)));
typedef __bf16 bf16x4 __attribute__((ext_vector_type(4)));
typedef __bf16 bf16x2 __attribute__((ext_vector_type(2)));
typedef float f32x4 __attribute__((ext_vector_type(4)));

__device__ __forceinline__ void gload_lds16(const void* g, void* l) {
  __builtin_amdgcn_global_load_lds(
      (const __attribute__((address_space(1))) void*)(uintptr_t)g,
      (__attribute__((address_space(3))) void*)(uintptr_t)l, 16, 0, 0);
}

#define SCHEDB() __builtin_amdgcn_sched_barrier(0)
#define BARx()   __builtin_amdgcn_s_barrier()
#define LGKM0() do { asm volatile("s_waitcnt lgkmcnt(0)" ::: "memory"); SCHEDB(); } while (0)
#define VMC(N)  do { asm volatile("s_waitcnt vmcnt(" #N ")" ::: "memory"); SCHEDB(); } while (0)

// ---------------- K0: fused preprocessing: cast x + transpose both weights --
__global__ __launch_bounds__(256) void k_pre(const float* __restrict__ x,
    __hip_bfloat16* __restrict__ xb, const float* __restrict__ in_w,
    __hip_bfloat16* __restrict__ wib, const float* __restrict__ out_w,
    __hip_bfloat16* __restrict__ wob) {
  __shared__ float s[64][65];
  int bid = blockIdx.x;
  if (bid < 8192) {                       // cast x -> bf16
    int i = (bid * 256 + threadIdx.x) * 4;
    float4 v = *(const float4*)(x + i);
    bf16x4 r;
    r[0] = (__bf16)v.x; r[1] = (__bf16)v.y; r[2] = (__bf16)v.z; r[3] = (__bf16)v.w;
    *(bf16x4*)(xb + i) = r;
    return;
  }
  const float* w; __hip_bfloat16* wt;
  int K, ldsrc, colOff, ncols, kx, ny;
  if (bid < 8800) {                       // in_proj weight transpose
    int b2 = bid - 8192; kx = b2 & 15; ny = b2 >> 4;
    w = in_w; wt = wib; K = DM; ldsrc = DPROJ; colOff = PROJ_OFF; ncols = NPROJ;
  } else {                                // out_proj weight transpose
    int b3 = bid - 8800; kx = b3 & 31; ny = b3 >> 5;
    w = out_w; wt = wob; K = DIN; ldsrc = DM; colOff = 0; ncols = DM;
  }
  int k0 = kx * 64, n0 = ny * 64;
  int c = threadIdx.x & 63, r0 = threadIdx.x >> 6;
  for (int i = 0; i < 16; i++) {
    int r = r0 + 4 * i;
    int ng = n0 + c;
    s[r][c] = (ng < ncols) ? w[(size_t)(k0 + r) * ldsrc + colOff + ng] : 0.f;
  }
  __syncthreads();
  for (int i = 0; i < 16; i++) {
    int a = r0 + 4 * i;
    wt[(size_t)(n0 + a) * K + k0 + c] = __float2bfloat16(s[c][a]);
  }
}

// ---------------- MFMA GEMM v7: 128x128, dbuf, read/MFMA OVERLAPPED --------
// Round-4 lesson: explicit lgkmcnt(0) between the 16 ds_reads and the first
// MFMA serialized the LDS phase (1536 cyc) against the MFMA phase (1241 cyc).
// v7 ordering per K-step:
//   ds_reads (C++ loads) -> 32 MFMA (compiler emits COUNTED lgkm per
//   first-use, so MFMA k-slice 0 starts while slice-1 frags are in flight)
//   -> lgkm0 (no-op by then) -> barrier (buffer free) -> stage(it+2 -> cur
//   buffer) -> counted VMC guard -> barrier.
// vmcnt ledger identical to round 4 (8 loads/stage, in-order):
//   steady (it < nIter-2): outstanding 16 -> VMC(8) drains stage(it-1)
//     which feeds iter it+1; this iter's 8 stay in flight.
//   it == nIter-2: stage skipped -> outstanding 8 = the last buffer's loads
//     -> VMC(0) full drain.  it == nIter-1: nothing outstanding.
template <int KDIM, bool SPLIT, int NTN>
__global__ __launch_bounds__(256) void k_gemmp(
    const __hip_bfloat16* __restrict__ A, const __hip_bfloat16* __restrict__ Bt,
    float* __restrict__ C, __hip_bfloat16* __restrict__ Cb16,
    float* __restrict__ dtb, const float* __restrict__ dt_bias, int NLD) {
  __shared__ __attribute__((aligned(16))) __hip_bfloat16 sA[2][128 * 64];
  __shared__ __attribute__((aligned(16))) __hip_bfloat16 sB[2][128 * 64];
  int tid = threadIdx.x;
  int wid = tid >> 6, lane = tid & 63;
  // T1: bijective XCD swizzle (gridDim.x divisible by 8)
  int f = blockIdx.x;
  int wg = (f & 7) * ((int)gridDim.x >> 3) + (f >> 3);
  int t0 = (wg / NTN) * 128, n0 = (wg % NTN) * 128;
  int wm = (wid >> 1) * 64, wn = (wid & 1) * 64;
  int r15 = lane & 15, quad = lane >> 4;
  int srow = lane >> 3;
  int kcs = lane & 7;

  f32x4 acc[4][4];
  f32x4 zz = {0.f, 0.f, 0.f, 0.f};
  for (int ni = 0; ni < 4; ni++)
    for (int ti = 0; ti < 4; ti++) acc[ni][ti] = zz;

  const __hip_bfloat16* Abase = A + (size_t)t0 * KDIM;
  const __hip_bfloat16* Bbase = Bt + (size_t)n0 * KDIM;

  auto stage = [&](int bb, int k0) {
#pragma unroll
    for (int c = 0; c < 4; c++) {
      int R0 = (wid * 4 + c) * 8;
      int row = R0 + srow;
      int kcg = kcs ^ (row & 7);
      gload_lds16(Abase + (size_t)row * KDIM + k0 + kcg * 8, &sA[bb][R0 * 64]);
      gload_lds16(Bbase + (size_t)row * KDIM + k0 + kcg * 8, &sB[bb][R0 * 64]);
    }
  };

  // prologue: two tiles in flight; wait only for the first
  stage(0, 0);
  stage(1, 64);
  VMC(8);
  BARx(); SCHEDB();

  const int nIter = KDIM / 64;
  for (int it = 0; it < nIter; ++it) {
    const int bb = it & 1;
    // 1) fragment loads + MFMA, interleaved BY THE COMPILER (counted lgkm):
    //    no explicit wait between them — reads are ordinary loads, MFMAs are
    //    gated per-first-use, so k-slice-0 MFMAs overlap k-slice-1 LDS reads.
    bf16x8 wf[4][2], xf[4][2];
#pragma unroll
    for (int s = 0; s < 2; s++) {
      int sw = ((s << 2) | quad) ^ (r15 & 7);
#pragma unroll
      for (int ni = 0; ni < 4; ni++)
        wf[ni][s] = *reinterpret_cast<const bf16x8*>(&sB[bb][(wn + ni * 16 + r15) * 64 + sw * 8]);
#pragma unroll
      for (int ti = 0; ti < 4; ti++)
        xf[ti][s] = *reinterpret_cast<const bf16x8*>(&sA[bb][(wm + ti * 16 + r15) * 64 + sw * 8]);
    }
#pragma unroll
    for (int s = 0; s < 2; s++)
#pragma unroll
      for (int ni = 0; ni < 4; ni++)
#pragma unroll
        for (int ti = 0; ti < 4; ti++)
          acc[ni][ti] = __builtin_amdgcn_mfma_f32_16x16x32_bf16(wf[ni][s], xf[ti][s], acc[ni][ti], 0, 0, 0);
    // 2) own reads certainly retired; publish "buffer free" to all waves
    LGKM0();
    BARx(); SCHEDB();
    // 3) refill cur buffer for iteration it+2 (async, ~1.5-iteration lead)
    if (it + 2 < nIter) stage(bb, (it + 2) * 64);
    // 4) guard the next buffer's staging loads (see ledger above)
    if (it < nIter - 2) {
      VMC(8);
      BARx(); SCHEDB();
    } else if (it == nIter - 2) {
      VMC(0);                      // last buffer's loads: full drain
      BARx(); SCHEDB();
    }
    // it == nIter-1: fall through to epilogue, nothing outstanding
  }

  // epilogue: D[n = quad*4+i][t = r15], vector stores over n
#pragma unroll
  for (int ni = 0; ni < 4; ni++) {
    int n = n0 + wn + ni * 16 + quad * 4;
#pragma unroll
    for (int ti = 0; ti < 4; ti++) {
      int t = t0 + wm + ti * 16 + r15;
      f32x4 v = acc[ni][ti];
      if (SPLIT) {
        if (n < CONVD) {
          bf16x4 r;
#pragma unroll
          for (int i = 0; i < 4; i++) r[i] = (__bf16)v[i];
          *(bf16x4*)(Cb16 + (size_t)t * CONVD + n) = r;
        } else if (n < NPROJ) {     // [CONVD, NPROJ) — 4-aligned boundary
#pragma unroll
          for (int i = 0; i < 4; i++) {
            int h = n + i - CONVD;
            float z = v[i] + dt_bias[h];
            float sp = (z > 20.f) ? z : log1pf(__expf(z));
            dtb[t * NH + h] = sp;
          }
        }
        // n >= NPROJ: zero-padded columns, discarded
      } else {
        *(float4*)(C + (size_t)t * NLD + n) = *(float4*)&v;
      }
    }
  }
}

// ---------------- K2: depthwise causal conv(4) + bias + SiLU (4 ch/thread) --
__global__ __launch_bounds__(256) void k_conv(const __hip_bfloat16* __restrict__ xbc,
    const float* __restrict__ cw, const float* __restrict__ cb,
    __hip_bfloat16* __restrict__ xh, __hip_bfloat16* __restrict__ Bm,
    __hip_bfloat16* __restrict__ Cm) {
  int pi = blockIdx.x * 256 + threadIdx.x;
  if (pi >= CONVD / 4) return;
  int ch = pi * 4;
  int t = blockIdx.y;
  int l = t & (L_SEQ - 1);
  float4 cb4 = *(const float4*)(cb + ch);
  float acc[4] = {cb4.x, cb4.y, cb4.z, cb4.w};
#pragma unroll
  for (int j = 0; j < 4; j++) {
    int ls = l - 3 + j;
    if (ls >= 0) {
      bf16x4 v = *(const bf16x4*)(xbc + (size_t)(t - 3 + j) * CONVD + ch);
      float4 w4 = *(const float4*)(cw + j * CONVD + ch);
      acc[0] += (float)v[0] * w4.x;
      acc[1] += (float)v[1] * w4.y;
      acc[2] += (float)v[2] * w4.z;
      acc[3] += (float)v[3] * w4.w;
    }
  }
  bf16x4 r;
#pragma unroll
  for (int i = 0; i < 4; i++) {
    float sv = acc[i] / (1.f + __expf(-acc[i]));
    r[i] = (__bf16)sv;
  }
  if (ch < DIN)                 *(bf16x4*)(xh + (size_t)t * DIN + ch) = r;
  else if (ch < DIN + DSTATE)   *(bf16x4*)(Bm + (size_t)t * DSTATE + ch - DIN) = r;
  else                          *(bf16x4*)(Cm + (size_t)t * DSTATE + ch - DIN - DSTATE) = r;
}

// ---------------- K4: fused SSD per (chunk, 8 heads), acum folded in --------
// All transposed LDS arrays use stride-64 XOR-granule layout: element (row, k)
// stored at row*64 + ((k>>3)^(row&7))*8 + (k&7). Store/read swizzles cancel.
__global__ __launch_bounds__(256) void k_ssd1(
    const __hip_bfloat16* __restrict__ xh, const __hip_bfloat16* __restrict__ Bm,
    const __hip_bfloat16* __restrict__ Cm, const float* __restrict__ dtb,
    const float* __restrict__ A_log, const float* __restrict__ Dp,
    __hip_bfloat16* __restrict__ ypart, __hip_bfloat16* __restrict__ statesT,
    float* __restrict__ acum_out, float* __restrict__ echunk) {
  __shared__ __attribute__((aligned(16))) char smem[32768 + 8192 + 6144];
  __hip_bfloat16* Cb  = (__hip_bfloat16*)smem;            // 64x128 swz (phase 1)
  __hip_bfloat16* Bb  = Cb + 64 * 128;                    // 64x128 swz (phase 1)
  __hip_bfloat16* BT  = (__hip_bfloat16*)smem;            // 128x64 [n][l] (phase 2, alias)
  __hip_bfloat16* xdT = BT + 128 * 64;                    // 64x64 [p][l] x*dt
  __hip_bfloat16* xsT = xdT + 64 * 64;                    // 64x64 [p][l] x*dt*dec
  __hip_bfloat16* P   = (__hip_bfloat16*)(smem + 32768);  // 64x64 [l][s]
  float* acvA = (float*)(smem + 32768 + 8192);            // [8][64]
  float* dtsA = acvA + 512;
  float* decA = dtsA + 512;

  int bc = blockIdx.x, h0 = blockIdx.y * 8;
  int base = bc * CH;
  int tid = threadIdx.x, wid = tid >> 6, lane = tid & 63;
  int r15 = lane & 15, quad = lane >> 4;
  int wm = wid * 16;
  f32x4 zz = {0.f, 0.f, 0.f, 0.f};

  // stage Cb/Bb via async gload (row-granule XOR swizzle on global side)
  {
    int srow = lane >> 4, g = lane & 15;
    for (int c = 0; c < 4; c++) {
      int R0 = wid * 16 + c * 4;
      int r = R0 + srow;
      int gs = g ^ (r & 7);
      gload_lds16(Cm + (size_t)(base + r) * DSTATE + gs * 8, &Cb[R0 * DSTATE]);
      gload_lds16(Bm + (size_t)(base + r) * DSTATE + gs * 8, &Bb[R0 * DSTATE]);
    }
  }
  // preload dt (8 heads x 64 positions)
  for (int i = 0; i < 2; i++) {
    int idx = tid + 256 * i;
    int hh = idx >> 6, l = idx & 63;
    dtsA[hh * 64 + l] = dtb[(base + l) * NH + h0 + hh];
  }
  __syncthreads();
  // in-block cumsum of A*dt (one serial lane per head; 64 fp32 adds)
  if (tid < 8) {
    int h = h0 + tid;
    float a = -__expf(A_log[h]);
    float s = 0.f;
    for (int l = 0; l < CH; l++) {
      s += a * dtsA[tid * 64 + l];
      acvA[tid * 64 + l] = s;
    }
    echunk[bc * NH + h] = __expf(s);
  }
  __syncthreads();
  // dec + persist acum for k_ssd2
  for (int i = 0; i < 2; i++) {
    int idx = tid + 256 * i;
    int hh = idx >> 6, l = idx & 63;
    float a = acvA[hh * 64 + l];
    decA[hh * 64 + l] = __expf(acvA[hh * 64 + 63] - a);
    acum_out[(base + l) * NH + h0 + hh] = a;
  }

  // --- G = C.B^T once: wave strip rows wm..wm+15 x all 64 s (K=128)
  f32x4 accg[4];
  for (int ct = 0; ct < 4; ct++) accg[ct] = zz;
#pragma unroll
  for (int ks = 0; ks < 4; ks++) {
    int arow = wm + r15;
    bf16x8 af = *(const bf16x8*)&Cb[arow * 128 + (((ks * 4 + quad) ^ (r15 & 7)) << 3)];
#pragma unroll
    for (int ct = 0; ct < 4; ct++) {
      int brow = ct * 16 + r15;
      bf16x8 bfr = *(const bf16x8*)&Bb[brow * 128 + (((ks * 4 + quad) ^ (r15 & 7)) << 3)];
      accg[ct] = __builtin_amdgcn_mfma_f32_16x16x32_bf16(af, bfr, accg[ct], 0, 0, 0);
    }
  }
  __syncthreads();   // Cb/Bb dead; region reused below

  int l0 = (tid & 15) * 4;     // 4 consecutive l (same granule: l0%8 in {0,4})
  int q0 = tid >> 4;           // 0..15
  int go = l0 & 7;             // offset within granule
  int gl = l0 >> 3;            // true granule of l0

  for (int hh = 0; hh < 8; hh++) {
    int h = h0 + hh;
    if (hh == 0) {
      // build BT[n][l] once (head-independent, decay folded into xs)
      int n0 = q0 * 8;
      __bf16 tmp[8][4];
#pragma unroll
      for (int dl = 0; dl < 4; dl++) {
        bf16x8 bv = *(const bf16x8*)(Bm + (size_t)(base + l0 + dl) * DSTATE + n0);
#pragma unroll
        for (int dn = 0; dn < 8; dn++) tmp[dn][dl] = bv[dn];
      }
#pragma unroll
      for (int dn = 0; dn < 8; dn++) {
        int n = n0 + dn;
        bf16x4 pk = {tmp[dn][0], tmp[dn][1], tmp[dn][2], tmp[dn][3]};
        *(bf16x4*)&BT[n * 64 + ((gl ^ (n & 7)) << 3) + go] = pk;
      }
    }
    // build xdT (x*dt) and xsT (x*dt*dec) for this head: 4l x 4p per thread
    {
      int p0 = q0 * 4;
      __bf16 td[4][4], ts[4][4];
#pragma unroll
      for (int dl = 0; dl < 4; dl++) {
        int l = l0 + dl;
        bf16x4 xv = *(const bf16x4*)(xh + (size_t)(base + l) * DIN + h * HD + p0);
        float dt = dtsA[hh * 64 + l];
        float ds = dt * decA[hh * 64 + l];
#pragma unroll
        for (int dp = 0; dp < 4; dp++) {
          float xf = (float)xv[dp];
          td[dp][dl] = (__bf16)(xf * dt);
          ts[dp][dl] = (__bf16)(xf * ds);
        }
      }
#pragma unroll
      for (int dp = 0; dp < 4; dp++) {
        int p = p0 + dp;
        int off = p * 64 + ((gl ^ (p & 7)) << 3) + go;
        bf16x4 pd = {td[dp][0], td[dp][1], td[dp][2], td[dp][3]};
        bf16x4 ps = {ts[dp][0], ts[dp][1], ts[dp][2], ts[dp][3]};
        *(bf16x4*)&xdT[off] = pd;
        *(bf16x4*)&xsT[off] = ps;
      }
    }
    __syncthreads();

    // --- P = mask(G * decay) -> LDS (wave-private rows wm..wm+15)
#pragma unroll
    for (int ct = 0; ct < 4; ct++) {
      int s = ct * 16 + r15;
      float as = acvA[hh * 64 + s];
#pragma unroll
      for (int i = 0; i < 4; i++) {
        int l = wm + quad * 4 + i;
        float pv = (s <= l) ? accg[ct][i] * __expf(acvA[hh * 64 + l] - as) : 0.f;
        P[l * 64 + (((s >> 3) ^ (l & 7)) << 3) + (s & 7)] = __float2bfloat16(pv);
      }
    }
    // --- Y_diag = P.xd (K=64) + xh*D
    f32x4 accy[4];
    for (int ct = 0; ct < 4; ct++) accy[ct] = zz;
#pragma unroll
    for (int ks = 0; ks < 2; ks++) {
      int arow = wm + r15;
      bf16x8 af = *(const bf16x8*)&P[arow * 64 + (((ks * 4 + quad) ^ (r15 & 7)) << 3)];
#pragma unroll
      for (int ct = 0; ct < 4; ct++) {
        int brow = ct * 16 + r15;
        bf16x8 bfr = *(const bf16x8*)&xdT[brow * 64 + (((ks * 4 + quad) ^ (r15 & 7)) << 3)];
        accy[ct] = __builtin_amdgcn_mfma_f32_16x16x32_bf16(af, bfr, accy[ct], 0, 0, 0);
      }
    }
    float Dh = Dp[h];
#pragma unroll
    for (int ct = 0; ct < 4; ct++) {
      int p = ct * 16 + r15;
#pragma unroll
      for (int i = 0; i < 4; i++) {
        int l = wm + quad * 4 + i;
        float xv = __bfloat162float(xh[(size_t)(base + l) * DIN + h * HD + p]);
        ypart[(size_t)(base + l) * DIN + h * HD + p] = __float2bfloat16(accy[ct][i] + xv * Dh);
      }
    }
    // --- S^T[p][n] = sum_l xs[l][p] * B[l][n]  (K=64, wave strip over p)
    f32x4 accs[8];
    for (int ct = 0; ct < 8; ct++) accs[ct] = zz;
#pragma unroll
    for (int ks = 0; ks < 2; ks++) {
      int arow = wm + r15;   // p row
      bf16x8 af = *(const bf16x8*)&xsT[arow * 64 + (((ks * 4 + quad) ^ (r15 & 7)) << 3)];
#pragma unroll
      for (int ct = 0; ct < 8; ct++) {
        int brow = ct * 16 + r15;   // n row
        bf16x8 bfr = *(const bf16x8*)&BT[brow * 64 + (((ks * 4 + quad) ^ (r15 & 7)) << 3)];
        accs[ct] = __builtin_amdgcn_mfma_f32_16x16x32_bf16(af, bfr, accs[ct], 0, 0, 0);
      }
    }
    size_t sbase = ((size_t)bc * NH + h) * (HD * DSTATE);
#pragma unroll
    for (int ct = 0; ct < 8; ct++) {
      int n = ct * 16 + r15;
#pragma unroll
      for (int i = 0; i < 4; i++) {
        int p = wm + quad * 4 + i;
        statesT[sbase + (size_t)p * DSTATE + n] = __float2bfloat16(accs[ct][i]);
      }
    }
    __syncthreads();   // before next head overwrites xdT/xsT
  }
}

// ---------------- K5: inter-chunk scan (in-place, 4 elems/thread, bf16x4) --
// Widened 4B -> 8B per lane (G13) + manual next-chunk prefetch so the load
// of chunk c+1 is in flight while chunk c is stored/updated.
__global__ __launch_bounds__(256) void k_scan(__hip_bfloat16* __restrict__ states,
    const float* __restrict__ echunk) {
  int idx = blockIdx.x * 256 + threadIdx.x;   // 131072
  int inner = (idx & 2047) * 4;    // p*128+n, quad-aligned
  int h = (idx >> 11) & 31;
  int b = idx >> 16;
  float run0 = 0.f, run1 = 0.f, run2 = 0.f, run3 = 0.f;
  size_t off = ((size_t)(b * NCH) * NH + h) * 8192 + inner;
  const size_t cstride = (size_t)NH * 8192;
  bf16x4 v = *(bf16x4*)(states + off);
  for (int c = 0; c < NCH; c++) {
    bf16x4 vn;
    if (c + 1 < NCH) vn = *(bf16x4*)(states + off + cstride);   // prefetch
    float e = echunk[(b * NCH + c) * NH + h];
    bf16x4 w = {(__bf16)run0, (__bf16)run1, (__bf16)run2, (__bf16)run3};
    *(bf16x4*)(states + off) = w;
    run0 = run0 * e + (float)v[0];
    run1 = run1 * e + (float)v[1];
    run2 = run2 * e + (float)v[2];
    run3 = run3 * e + (float)v[3];
    v = vn;
    off += cstride;
  }
}

// ---------------- K6: y += exp(acum)*(C.S_in^T), 4 heads/block, C reused ---
__global__ __launch_bounds__(256) void k_ssd2(
    const __hip_bfloat16* __restrict__ statesT, const __hip_bfloat16* __restrict__ Cm,
    const float* __restrict__ acum, __hip_bfloat16* __restrict__ y) {
  __shared__ __attribute__((aligned(16))) __hip_bfloat16 Cb[64 * 128];  // [l][n] swz
  __shared__ __attribute__((aligned(16))) __hip_bfloat16 Sb[64 * 128];  // [p][n] swz
  __shared__ __attribute__((aligned(16))) __hip_bfloat16 Yt[64 * 64];   // [l][p]
  __shared__ float aout[4 * 64];
  int bc = blockIdx.x, h0 = blockIdx.y * 4;
  int base = bc * CH;
  int tid = threadIdx.x, wid = tid >> 6, lane = tid & 63;
  int r15 = lane & 15, quad = lane >> 4;
  int wm = wid * 16;
  int srow = lane >> 4, g = lane & 15;

  aout[tid] = __expf(acum[(base + (tid & 63)) * NH + h0 + (tid >> 6)]);
  // stage Cb once (reused for all 4 heads)
  for (int c = 0; c < 4; c++) {
    int R0 = wid * 16 + c * 4;
    int r = R0 + srow;
    int gs = g ^ (r & 7);
    gload_lds16(Cm + (size_t)(base + r) * DSTATE + gs * 8, &Cb[R0 * DSTATE]);
  }

  for (int hh = 0; hh < 4; hh++) {
    int h = h0 + hh;
    size_t sbase = ((size_t)bc * NH + h) * (HD * DSTATE);
    // stage Sb + Yt for this head
    for (int c = 0; c < 4; c++) {
      int R0 = wid * 16 + c * 4;
      int r = R0 + srow;
      int gs = g ^ (r & 7);
      gload_lds16(statesT + sbase + (size_t)r * DSTATE + gs * 8, &Sb[R0 * DSTATE]);
    }
    for (int c = 0; c < 2; c++) {
      int R0 = wid * 16 + c * 8;
      int r = R0 + (lane >> 3);
      gload_lds16(y + (size_t)(base + r) * DIN + h * HD + (lane & 7) * 8, &Yt[R0 * 64]);
    }
    __syncthreads();

    f32x4 acc[4];
    f32x4 zz = {0.f, 0.f, 0.f, 0.f};
    for (int ct = 0; ct < 4; ct++) acc[ct] = zz;
#pragma unroll
    for (int ks = 0; ks < 4; ks++) {
      int arow = wm + r15;
      bf16x8 af = *(const bf16x8*)&Cb[arow * 128 + (((ks * 4 + quad) ^ (r15 & 7)) << 3)];
#pragma unroll
      for (int ct = 0; ct < 4; ct++) {
        int brow = ct * 16 + r15;
        bf16x8 bfr = *(const bf16x8*)&Sb[brow * 128 + (((ks * 4 + quad) ^ (r15 & 7)) << 3)];
        acc[ct] = __builtin_amdgcn_mfma_f32_16x16x32_bf16(af, bfr, acc[ct], 0, 0, 0);
      }
    }
#pragma unroll
    for (int ct = 0; ct < 4; ct++) {
      int p = ct * 16 + r15;
#pragma unroll
      for (int i = 0; i < 4; i++) {
        int l = wm + quad * 4 + i;
        float v = __bfloat162float(Yt[l * 64 + p]) + aout[hh * 64 + l] * acc[ct][i];
        y[(size_t)(base + l) * DIN + h * HD + p] = __float2bfloat16(v);
      }
    }
    __syncthreads();   // before next head's staging overwrites Sb/Yt
  }
}

extern "C" void kernel_launch(void* const* d_in, const int* in_sizes, int n_in,
                              void* d_out, int out_size, void* d_ws, size_t ws_size,
                              hipStream_t stream) {
  const float* x       = (const float*)d_in[0];
  const float* in_w    = (const float*)d_in[1];
  const float* conv_w  = (const float*)d_in[2];
  const float* conv_b  = (const float*)d_in[3];
  const float* dt_bias = (const float*)d_in[4];
  const float* A_log   = (const float*)d_in[5];
  const float* Dp      = (const float*)d_in[6];
  const float* out_w   = (const float*)d_in[7];
  float* out = (float*)d_out;

  char* cur = (char*)d_ws;
  auto alloc = [&](size_t bytes) {
    char* p = cur;
    cur += (bytes + 255) & ~(size_t)255;
    return p;
  };
  __hip_bfloat16* xbc   = (__hip_bfloat16*)alloc((size_t)T_TOK * CONVD * 2);
  float* dtb            = (float*)alloc((size_t)T_TOK * NH * 4);
  float* acum           = (float*)alloc((size_t)T_TOK * NH * 4);
  float* echunk         = (float*)alloc((size_t)NBC * NH * 4);
  __hip_bfloat16* xh    = (__hip_bfloat16*)alloc((size_t)T_TOK * DIN * 2);
  __hip_bfloat16* Bm    = (__hip_bfloat16*)alloc((size_t)T_TOK * DSTATE * 2);
  __hip_bfloat16* Cm    = (__hip_bfloat16*)alloc((size_t)T_TOK * DSTATE * 2);
  __hip_bfloat16* ybuf  = (__hip_bfloat16*)alloc((size_t)T_TOK * DIN * 2);
  __hip_bfloat16* states= (__hip_bfloat16*)alloc((size_t)NBC * NH * HD * DSTATE * 2);
  __hip_bfloat16* wib   = (__hip_bfloat16*)alloc((size_t)NPAD * DM * 2);
  __hip_bfloat16* wob   = (__hip_bfloat16*)alloc((size_t)DIN * DM * 2);
  __hip_bfloat16* xb    = states;   // alias: xb dead before k_ssd1 writes states

  k_pre    <<<dim3(9312), 256, 0, stream>>>(x, xb, in_w, wib, out_w, wob);
  k_gemmp<DM, true, NPAD / 128><<<dim3((NPAD / 128) * (T_TOK / 128)), 256, 0, stream>>>(
      xb, wib, nullptr, xbc, dtb, dt_bias, 0);
  k_conv   <<<dim3(3, T_TOK), 256, 0, stream>>>(xbc, conv_w, conv_b, xh, Bm, Cm);
  k_ssd1   <<<dim3(NBC, 4),   256, 0, stream>>>(xh, Bm, Cm, dtb, A_log, Dp, ybuf, states, acum, echunk);
  k_scan   <<<dim3(512),      256, 0, stream>>>(states, echunk);
  k_ssd2   <<<dim3(NBC, 8),   256, 0, stream>>>(states, Cm, acum, ybuf);
  k_gemmp<DIN, false, DM / 128><<<dim3((DM / 128) * (T_TOK / 128)), 256, 0, stream>>>(
      ybuf, wob, out, nullptr, nullptr, nullptr, DM);
}

// Round 6
// 342.832 us; speedup vs baseline: 1.0043x; 1.0043x over previous
//
#include <hip/hip_runtime.h>
#include <hip/hip_bf16.h>
#include <math.h>
#include <stdint.h>

#define T_TOK 8192      // b*l
#define L_SEQ 4096
#define DM    1024
#define DIN   2048
#define DSTATE 128
#define NH    32
#define HD    64
#define CH    64        // chunk length
#define NCH   64        // chunks per batch
#define NBC   128       // B * NCH
#define CONVD 2304
#define NPROJ 2336      // columns of in_proj we actually need (z gate unused)
#define NPAD  2432      // NPROJ padded to multiple of 128
#define PROJ_OFF 2048
#define DPROJ 4384

typedef __bf16 bf16x8 __attribute__((ext_vector_type(8)));
typedef __bf16 bf16x4 __attribute__((ext_vector_type(4)));
typedef __bf16 bf16x2 __attribute__((ext_vector_type(2)));
typedef float f32x4 __attribute__((ext_vector_type(4)));

__device__ __forceinline__ void gload_lds16(const void* g, void* l) {
  __builtin_amdgcn_global_load_lds(
      (const __attribute__((address_space(1))) void*)(uintptr_t)g,
      (__attribute__((address_space(3))) void*)(uintptr_t)l, 16, 0, 0);
}

#define SCHEDB() __builtin_amdgcn_sched_barrier(0)
#define BARx()   __builtin_amdgcn_s_barrier()
#define LGKM0() do { asm volatile("s_waitcnt lgkmcnt(0)" ::: "memory"); SCHEDB(); } while (0)
#define VMC(N)  do { asm volatile("s_waitcnt vmcnt(" #N ")" ::: "memory"); SCHEDB(); } while (0)

// ---------------- K0: fused preprocessing: cast x + transpose both weights --
__global__ __launch_bounds__(256) void k_pre(const float* __restrict__ x,
    __hip_bfloat16* __restrict__ xb, const float* __restrict__ in_w,
    __hip_bfloat16* __restrict__ wib, const float* __restrict__ out_w,
    __hip_bfloat16* __restrict__ wob) {
  __shared__ float s[64][65];
  int bid = blockIdx.x;
  if (bid < 8192) {                       // cast x -> bf16
    int i = (bid * 256 + threadIdx.x) * 4;
    float4 v = *(const float4*)(x + i);
    bf16x4 r;
    r[0] = (__bf16)v.x; r[1] = (__bf16)v.y; r[2] = (__bf16)v.z; r[3] = (__bf16)v.w;
    *(bf16x4*)(xb + i) = r;
    return;
  }
  const float* w; __hip_bfloat16* wt;
  int K, ldsrc, colOff, ncols, kx, ny;
  if (bid < 8800) {                       // in_proj weight transpose
    int b2 = bid - 8192; kx = b2 & 15; ny = b2 >> 4;
    w = in_w; wt = wib; K = DM; ldsrc = DPROJ; colOff = PROJ_OFF; ncols = NPROJ;
  } else {                                // out_proj weight transpose
    int b3 = bid - 8800; kx = b3 & 31; ny = b3 >> 5;
    w = out_w; wt = wob; K = DIN; ldsrc = DM; colOff = 0; ncols = DM;
  }
  int k0 = kx * 64, n0 = ny * 64;
  int c = threadIdx.x & 63, r0 = threadIdx.x >> 6;
  for (int i = 0; i < 16; i++) {
    int r = r0 + 4 * i;
    int ng = n0 + c;
    s[r][c] = (ng < ncols) ? w[(size_t)(k0 + r) * ldsrc + colOff + ng] : 0.f;
  }
  __syncthreads();
  for (int i = 0; i < 16; i++) {
    int a = r0 + 4 * i;
    wt[(size_t)(n0 + a) * K + k0 + c] = __float2bfloat16(s[c][a]);
  }
}

// ---------------- MFMA GEMM (round-4 proven structure, 67 µs) --------------
// reads -> lgkm0 -> barrier -> stage(it+2) -> MFMA -> counted VMC -> barrier.
// vmcnt ledger (8 loads/stage, in-order):
//   steady (it < nIter-2): outstanding 16 -> VMC(8) drains stage(it-1)
//     which feeds iter it+1; this iter's 8 stay in flight.
//   it == nIter-2: stage skipped -> outstanding 8 = last buffer's loads
//     -> VMC(0) full drain.  it == nIter-1: nothing outstanding.
// (Round-5 A/B: removing the lgkm0-before-MFMA and staging after MFMA
//  regressed 67->78 µs. This ordering is the local optimum of the 128² dbuf
//  structure; do not re-perturb without new counter evidence.)
template <int KDIM, bool SPLIT, int NTN>
__global__ __launch_bounds__(256) void k_gemmp(
    const __hip_bfloat16* __restrict__ A, const __hip_bfloat16* __restrict__ Bt,
    float* __restrict__ C, __hip_bfloat16* __restrict__ Cb16,
    float* __restrict__ dtb, const float* __restrict__ dt_bias, int NLD) {
  __shared__ __attribute__((aligned(16))) __hip_bfloat16 sA[2][128 * 64];
  __shared__ __attribute__((aligned(16))) __hip_bfloat16 sB[2][128 * 64];
  int tid = threadIdx.x;
  int wid = tid >> 6, lane = tid & 63;
  // T1: bijective XCD swizzle (gridDim.x divisible by 8)
  int f = blockIdx.x;
  int wg = (f & 7) * ((int)gridDim.x >> 3) + (f >> 3);
  int t0 = (wg / NTN) * 128, n0 = (wg % NTN) * 128;
  int wm = (wid >> 1) * 64, wn = (wid & 1) * 64;
  int r15 = lane & 15, quad = lane >> 4;
  int srow = lane >> 3;
  int kcs = lane & 7;

  f32x4 acc[4][4];
  f32x4 zz = {0.f, 0.f, 0.f, 0.f};
  for (int ni = 0; ni < 4; ni++)
    for (int ti = 0; ti < 4; ti++) acc[ni][ti] = zz;

  const __hip_bfloat16* Abase = A + (size_t)t0 * KDIM;
  const __hip_bfloat16* Bbase = Bt + (size_t)n0 * KDIM;

  auto stage = [&](int bb, int k0) {
#pragma unroll
    for (int c = 0; c < 4; c++) {
      int R0 = (wid * 4 + c) * 8;
      int row = R0 + srow;
      int kcg = kcs ^ (row & 7);
      gload_lds16(Abase + (size_t)row * KDIM + k0 + kcg * 8, &sA[bb][R0 * 64]);
      gload_lds16(Bbase + (size_t)row * KDIM + k0 + kcg * 8, &sB[bb][R0 * 64]);
    }
  };

  // prologue: two tiles in flight; wait only for the first
  stage(0, 0);
  stage(1, 64);
  VMC(8);
  BARx(); SCHEDB();

  const int nIter = KDIM / 64;
  for (int it = 0; it < nIter; ++it) {
    const int bb = it & 1;
    // 1) whole current tile -> registers
    bf16x8 wf[4][2], xf[4][2];
#pragma unroll
    for (int s = 0; s < 2; s++) {
      int sw = ((s << 2) | quad) ^ (r15 & 7);
#pragma unroll
      for (int ni = 0; ni < 4; ni++)
        wf[ni][s] = *reinterpret_cast<const bf16x8*>(&sB[bb][(wn + ni * 16 + r15) * 64 + sw * 8]);
#pragma unroll
      for (int ti = 0; ti < 4; ti++)
        xf[ti][s] = *reinterpret_cast<const bf16x8*>(&sA[bb][(wm + ti * 16 + r15) * 64 + sw * 8]);
    }
    LGKM0();            // own ds_reads complete
    BARx(); SCHEDB();   // all waves' reads complete -> cur buffer reusable
    // 2) refill cur buffer for iteration it+2 (async, ~2-iter lead)
    if (it + 2 < nIter) stage(bb, (it + 2) * 64);
    // 3) compute from registers
#pragma unroll
    for (int s = 0; s < 2; s++)
#pragma unroll
      for (int ni = 0; ni < 4; ni++)
#pragma unroll
        for (int ti = 0; ti < 4; ti++)
          acc[ni][ti] = __builtin_amdgcn_mfma_f32_16x16x32_bf16(wf[ni][s], xf[ti][s], acc[ni][ti], 0, 0, 0);
    // 4) guard the next buffer's staging loads (see ledger above)
    if (it < nIter - 2) {
      VMC(8);
      BARx(); SCHEDB();
    } else if (it == nIter - 2) {
      VMC(0);                      // last buffer's loads: full drain
      BARx(); SCHEDB();
    }
    // it == nIter-1: fall through to epilogue, nothing outstanding
  }

  // epilogue: D[n = quad*4+i][t = r15], vector stores over n
#pragma unroll
  for (int ni = 0; ni < 4; ni++) {
    int n = n0 + wn + ni * 16 + quad * 4;
#pragma unroll
    for (int ti = 0; ti < 4; ti++) {
      int t = t0 + wm + ti * 16 + r15;
      f32x4 v = acc[ni][ti];
      if (SPLIT) {
        if (n < CONVD) {
          bf16x4 r;
#pragma unroll
          for (int i = 0; i < 4; i++) r[i] = (__bf16)v[i];
          *(bf16x4*)(Cb16 + (size_t)t * CONVD + n) = r;
        } else if (n < NPROJ) {     // [CONVD, NPROJ) — 4-aligned boundary
#pragma unroll
          for (int i = 0; i < 4; i++) {
            int h = n + i - CONVD;
            float z = v[i] + dt_bias[h];
            float sp = (z > 20.f) ? z : log1pf(__expf(z));
            dtb[t * NH + h] = sp;
          }
        }
        // n >= NPROJ: zero-padded columns, discarded
      } else {
        *(float4*)(C + (size_t)t * NLD + n) = *(float4*)&v;
      }
    }
  }
}

// ---------------- K2: depthwise causal conv(4) + bias + SiLU (4 ch/thread) --
__global__ __launch_bounds__(256) void k_conv(const __hip_bfloat16* __restrict__ xbc,
    const float* __restrict__ cw, const float* __restrict__ cb,
    __hip_bfloat16* __restrict__ xh, __hip_bfloat16* __restrict__ Bm,
    __hip_bfloat16* __restrict__ Cm) {
  int pi = blockIdx.x * 256 + threadIdx.x;
  if (pi >= CONVD / 4) return;
  int ch = pi * 4;
  int t = blockIdx.y;
  int l = t & (L_SEQ - 1);
  float4 cb4 = *(const float4*)(cb + ch);
  float acc[4] = {cb4.x, cb4.y, cb4.z, cb4.w};
#pragma unroll
  for (int j = 0; j < 4; j++) {
    int ls = l - 3 + j;
    if (ls >= 0) {
      bf16x4 v = *(const bf16x4*)(xbc + (size_t)(t - 3 + j) * CONVD + ch);
      float4 w4 = *(const float4*)(cw + j * CONVD + ch);
      acc[0] += (float)v[0] * w4.x;
      acc[1] += (float)v[1] * w4.y;
      acc[2] += (float)v[2] * w4.z;
      acc[3] += (float)v[3] * w4.w;
    }
  }
  bf16x4 r;
#pragma unroll
  for (int i = 0; i < 4; i++) {
    float sv = acc[i] / (1.f + __expf(-acc[i]));
    r[i] = (__bf16)sv;
  }
  if (ch < DIN)                 *(bf16x4*)(xh + (size_t)t * DIN + ch) = r;
  else if (ch < DIN + DSTATE)   *(bf16x4*)(Bm + (size_t)t * DSTATE + ch - DIN) = r;
  else                          *(bf16x4*)(Cm + (size_t)t * DSTATE + ch - DIN - DSTATE) = r;
}

// ---------------- K4: fused SSD per (chunk, 8 heads), acum folded in --------
// All transposed LDS arrays use stride-64 XOR-granule layout: element (row, k)
// stored at row*64 + ((k>>3)^(row&7))*8 + (k&7). Store/read swizzles cancel.
// Round-6: epilogues vectorized via MFMA operand swap (contraction is
// symmetric): putting the memory-contiguous dim (p / n) on quad*4+i gives
// bf16x4 global accesses instead of scalar bf16 (Common-mistake #2).
// Output convention (verified against accg/P in this file): for
// mfma(af = X[strip wm+r15], bfr = Y[ct*16+r15]), element [ct][i] lands at
// (X-dim = wm+quad*4+i, Y-dim = ct*16+r15).
__global__ __launch_bounds__(256) void k_ssd1(
    const __hip_bfloat16* __restrict__ xh, const __hip_bfloat16* __restrict__ Bm,
    const __hip_bfloat16* __restrict__ Cm, const float* __restrict__ dtb,
    const float* __restrict__ A_log, const float* __restrict__ Dp,
    __hip_bfloat16* __restrict__ ypart, __hip_bfloat16* __restrict__ statesT,
    float* __restrict__ acum_out, float* __restrict__ echunk) {
  __shared__ __attribute__((aligned(16))) char smem[32768 + 8192 + 6144];
  __hip_bfloat16* Cb  = (__hip_bfloat16*)smem;            // 64x128 swz (phase 1)
  __hip_bfloat16* Bb  = Cb + 64 * 128;                    // 64x128 swz (phase 1)
  __hip_bfloat16* BT  = (__hip_bfloat16*)smem;            // 128x64 [n][l] (phase 2, alias)
  __hip_bfloat16* xdT = BT + 128 * 64;                    // 64x64 [p][l] x*dt
  __hip_bfloat16* xsT = xdT + 64 * 64;                    // 64x64 [p][l] x*dt*dec
  __hip_bfloat16* P   = (__hip_bfloat16*)(smem + 32768);  // 64x64 [l][s]
  float* acvA = (float*)(smem + 32768 + 8192);            // [8][64]
  float* dtsA = acvA + 512;
  float* decA = dtsA + 512;

  int bc = blockIdx.x, h0 = blockIdx.y * 8;
  int base = bc * CH;
  int tid = threadIdx.x, wid = tid >> 6, lane = tid & 63;
  int r15 = lane & 15, quad = lane >> 4;
  int wm = wid * 16;
  f32x4 zz = {0.f, 0.f, 0.f, 0.f};

  // stage Cb/Bb via async gload (row-granule XOR swizzle on global side)
  {
    int srow = lane >> 4, g = lane & 15;
    for (int c = 0; c < 4; c++) {
      int R0 = wid * 16 + c * 4;
      int r = R0 + srow;
      int gs = g ^ (r & 7);
      gload_lds16(Cm + (size_t)(base + r) * DSTATE + gs * 8, &Cb[R0 * DSTATE]);
      gload_lds16(Bm + (size_t)(base + r) * DSTATE + gs * 8, &Bb[R0 * DSTATE]);
    }
  }
  // preload dt (8 heads x 64 positions)
  for (int i = 0; i < 2; i++) {
    int idx = tid + 256 * i;
    int hh = idx >> 6, l = idx & 63;
    dtsA[hh * 64 + l] = dtb[(base + l) * NH + h0 + hh];
  }
  __syncthreads();
  // in-block cumsum of A*dt (one serial lane per head; 64 fp32 adds)
  if (tid < 8) {
    int h = h0 + tid;
    float a = -__expf(A_log[h]);
    float s = 0.f;
    for (int l = 0; l < CH; l++) {
      s += a * dtsA[tid * 64 + l];
      acvA[tid * 64 + l] = s;
    }
    echunk[bc * NH + h] = __expf(s);
  }
  __syncthreads();
  // dec + persist acum for k_ssd2
  for (int i = 0; i < 2; i++) {
    int idx = tid + 256 * i;
    int hh = idx >> 6, l = idx & 63;
    float a = acvA[hh * 64 + l];
    decA[hh * 64 + l] = __expf(acvA[hh * 64 + 63] - a);
    acum_out[(base + l) * NH + h0 + hh] = a;
  }

  // --- G = C.B^T once: wave strip rows wm..wm+15 x all 64 s (K=128)
  f32x4 accg[4];
  for (int ct = 0; ct < 4; ct++) accg[ct] = zz;
#pragma unroll
  for (int ks = 0; ks < 4; ks++) {
    int arow = wm + r15;
    bf16x8 af = *(const bf16x8*)&Cb[arow * 128 + (((ks * 4 + quad) ^ (r15 & 7)) << 3)];
#pragma unroll
    for (int ct = 0; ct < 4; ct++) {
      int brow = ct * 16 + r15;
      bf16x8 bfr = *(const bf16x8*)&Bb[brow * 128 + (((ks * 4 + quad) ^ (r15 & 7)) << 3)];
      accg[ct] = __builtin_amdgcn_mfma_f32_16x16x32_bf16(af, bfr, accg[ct], 0, 0, 0);
    }
  }
  __syncthreads();   // Cb/Bb dead; region reused below

  int l0 = (tid & 15) * 4;     // 4 consecutive l (same granule: l0%8 in {0,4})
  int q0 = tid >> 4;           // 0..15
  int go = l0 & 7;             // offset within granule
  int gl = l0 >> 3;            // true granule of l0

  for (int hh = 0; hh < 8; hh++) {
    int h = h0 + hh;
    if (hh == 0) {
      // build BT[n][l] once (head-independent, decay folded into xs)
      int n0 = q0 * 8;
      __bf16 tmp[8][4];
#pragma unroll
      for (int dl = 0; dl < 4; dl++) {
        bf16x8 bv = *(const bf16x8*)(Bm + (size_t)(base + l0 + dl) * DSTATE + n0);
#pragma unroll
        for (int dn = 0; dn < 8; dn++) tmp[dn][dl] = bv[dn];
      }
#pragma unroll
      for (int dn = 0; dn < 8; dn++) {
        int n = n0 + dn;
        bf16x4 pk = {tmp[dn][0], tmp[dn][1], tmp[dn][2], tmp[dn][3]};
        *(bf16x4*)&BT[n * 64 + ((gl ^ (n & 7)) << 3) + go] = pk;
      }
    }
    // build xdT (x*dt) and xsT (x*dt*dec) for this head: 4l x 4p per thread
    {
      int p0 = q0 * 4;
      __bf16 td[4][4], ts[4][4];
#pragma unroll
      for (int dl = 0; dl < 4; dl++) {
        int l = l0 + dl;
        bf16x4 xv = *(const bf16x4*)(xh + (size_t)(base + l) * DIN + h * HD + p0);
        float dt = dtsA[hh * 64 + l];
        float ds = dt * decA[hh * 64 + l];
#pragma unroll
        for (int dp = 0; dp < 4; dp++) {
          float xf = (float)xv[dp];
          td[dp][dl] = (__bf16)(xf * dt);
          ts[dp][dl] = (__bf16)(xf * ds);
        }
      }
#pragma unroll
      for (int dp = 0; dp < 4; dp++) {
        int p = p0 + dp;
        int off = p * 64 + ((gl ^ (p & 7)) << 3) + go;
        bf16x4 pd = {td[dp][0], td[dp][1], td[dp][2], td[dp][3]};
        bf16x4 ps = {ts[dp][0], ts[dp][1], ts[dp][2], ts[dp][3]};
        *(bf16x4*)&xdT[off] = pd;
        *(bf16x4*)&xsT[off] = ps;
      }
    }
    __syncthreads();

    // --- P = mask(G * decay) -> LDS (wave-private rows wm..wm+15)
#pragma unroll
    for (int ct = 0; ct < 4; ct++) {
      int s = ct * 16 + r15;
      float as = acvA[hh * 64 + s];
#pragma unroll
      for (int i = 0; i < 4; i++) {
        int l = wm + quad * 4 + i;
        float pv = (s <= l) ? accg[ct][i] * __expf(acvA[hh * 64 + l] - as) : 0.f;
        P[l * 64 + (((s >> 3) ^ (l & 7)) << 3) + (s & 7)] = __float2bfloat16(pv);
      }
    }
    __syncthreads();   // P now read CROSS-WAVE below (operand swap)

    // --- Y_diag via operand swap: out p = wm+quad*4+i, l = ct*16+r15
    f32x4 accy[4];
    for (int ct = 0; ct < 4; ct++) accy[ct] = zz;
#pragma unroll
    for (int ks = 0; ks < 2; ks++) {
      int arow = wm + r15;   // p strip
      bf16x8 af = *(const bf16x8*)&xdT[arow * 64 + (((ks * 4 + quad) ^ (r15 & 7)) << 3)];
#pragma unroll
      for (int ct = 0; ct < 4; ct++) {
        int brow = ct * 16 + r15;   // l rows (cross-wave)
        bf16x8 bfr = *(const bf16x8*)&P[brow * 64 + (((ks * 4 + quad) ^ (r15 & 7)) << 3)];
        accy[ct] = __builtin_amdgcn_mfma_f32_16x16x32_bf16(af, bfr, accy[ct], 0, 0, 0);
      }
    }
    float Dh = Dp[h];
#pragma unroll
    for (int ct = 0; ct < 4; ct++) {
      int l = ct * 16 + r15;
      int p0 = wm + quad * 4;
      const bf16x4 xv = *(const bf16x4*)(xh + (size_t)(base + l) * DIN + h * HD + p0);
      bf16x4 r;
#pragma unroll
      for (int i = 0; i < 4; i++)
        r[i] = (__bf16)(accy[ct][i] + (float)xv[i] * Dh);
      *(bf16x4*)(ypart + (size_t)(base + l) * DIN + h * HD + p0) = r;
    }
    // --- S^T[p][n] via operand swap: out n = hs*64+wm+quad*4+i, p = ct*16+r15
    f32x4 accs[2][4];
    for (int hs = 0; hs < 2; hs++)
      for (int ct = 0; ct < 4; ct++) accs[hs][ct] = zz;
#pragma unroll
    for (int ks = 0; ks < 2; ks++) {
#pragma unroll
      for (int hs = 0; hs < 2; hs++) {
        int arow = hs * 64 + wm + r15;   // n strip
        bf16x8 af = *(const bf16x8*)&BT[arow * 64 + (((ks * 4 + quad) ^ (r15 & 7)) << 3)];
#pragma unroll
        for (int ct = 0; ct < 4; ct++) {
          int brow = ct * 16 + r15;      // p rows
          bf16x8 bfr = *(const bf16x8*)&xsT[brow * 64 + (((ks * 4 + quad) ^ (r15 & 7)) << 3)];
          accs[hs][ct] = __builtin_amdgcn_mfma_f32_16x16x32_bf16(af, bfr, accs[hs][ct], 0, 0, 0);
        }
      }
    }
    size_t sbase = ((size_t)bc * NH + h) * (HD * DSTATE);
#pragma unroll
    for (int hs = 0; hs < 2; hs++) {
#pragma unroll
      for (int ct = 0; ct < 4; ct++) {
        int p = ct * 16 + r15;
        int n0 = hs * 64 + wm + quad * 4;
        bf16x4 r;
#pragma unroll
        for (int i = 0; i < 4; i++) r[i] = (__bf16)accs[hs][ct][i];
        *(bf16x4*)(statesT + sbase + (size_t)p * DSTATE + n0) = r;
      }
    }
    __syncthreads();   // before next head overwrites xdT/xsT
  }
}

// ---------------- K5: inter-chunk scan (in-place, 4 elems/thread, bf16x4) --
__global__ __launch_bounds__(256) void k_scan(__hip_bfloat16* __restrict__ states,
    const float* __restrict__ echunk) {
  int idx = blockIdx.x * 256 + threadIdx.x;   // 131072
  int inner = (idx & 2047) * 4;    // p*128+n, quad-aligned
  int h = (idx >> 11) & 31;
  int b = idx >> 16;
  float run0 = 0.f, run1 = 0.f, run2 = 0.f, run3 = 0.f;
  size_t off = ((size_t)(b * NCH) * NH + h) * 8192 + inner;
  const size_t cstride = (size_t)NH * 8192;
  bf16x4 v = *(bf16x4*)(states + off);
  for (int c = 0; c < NCH; c++) {
    bf16x4 vn;
    if (c + 1 < NCH) vn = *(bf16x4*)(states + off + cstride);   // prefetch
    float e = echunk[(b * NCH + c) * NH + h];
    bf16x4 w = {(__bf16)run0, (__bf16)run1, (__bf16)run2, (__bf16)run3};
    *(bf16x4*)(states + off) = w;
    run0 = run0 * e + (float)v[0];
    run1 = run1 * e + (float)v[1];
    run2 = run2 * e + (float)v[2];
    run3 = run3 * e + (float)v[3];
    v = vn;
    off += cstride;
  }
}

// ---------------- K6: y += exp(acum)*(C.S_in^T), 4 heads/block, C reused ---
// Round-6: operand-swapped epilogue (out p = wm+quad*4+i, l = ct*16+r15)
// -> bf16x4 y stores + bf16x4 Yt reads. Yt staged with source-granule XOR
// so the swapped read is bank-spread.
__global__ __launch_bounds__(256) void k_ssd2(
    const __hip_bfloat16* __restrict__ statesT, const __hip_bfloat16* __restrict__ Cm,
    const float* __restrict__ acum, __hip_bfloat16* __restrict__ y) {
  __shared__ __attribute__((aligned(16))) __hip_bfloat16 Cb[64 * 128];  // [l][n] swz
  __shared__ __attribute__((aligned(16))) __hip_bfloat16 Sb[64 * 128];  // [p][n] swz
  __shared__ __attribute__((aligned(16))) __hip_bfloat16 Yt[64 * 64];   // [l][p] swz
  __shared__ float aout[4 * 64];
  int bc = blockIdx.x, h0 = blockIdx.y * 4;
  int base = bc * CH;
  int tid = threadIdx.x, wid = tid >> 6, lane = tid & 63;
  int r15 = lane & 15, quad = lane >> 4;
  int wm = wid * 16;
  int srow = lane >> 4, g = lane & 15;

  aout[tid] = __expf(acum[(base + (tid & 63)) * NH + h0 + (tid >> 6)]);
  // stage Cb once (reused for all 4 heads)
  for (int c = 0; c < 4; c++) {
    int R0 = wid * 16 + c * 4;
    int r = R0 + srow;
    int gs = g ^ (r & 7);
    gload_lds16(Cm + (size_t)(base + r) * DSTATE + gs * 8, &Cb[R0 * DSTATE]);
  }

  for (int hh = 0; hh < 4; hh++) {
    int h = h0 + hh;
    size_t sbase = ((size_t)bc * NH + h) * (HD * DSTATE);
    // stage Sb + Yt for this head
    for (int c = 0; c < 4; c++) {
      int R0 = wid * 16 + c * 4;
      int r = R0 + srow;
      int gs = g ^ (r & 7);
      gload_lds16(statesT + sbase + (size_t)r * DSTATE + gs * 8, &Sb[R0 * DSTATE]);
    }
    for (int c = 0; c < 2; c++) {
      int R0 = wid * 16 + c * 8;
      int r = R0 + (lane >> 3);
      int g8 = (lane & 7) ^ (r & 7);          // source-granule XOR, dest linear
      gload_lds16(y + (size_t)(base + r) * DIN + h * HD + g8 * 8, &Yt[R0 * 64]);
    }
    __syncthreads();

    f32x4 acc[4];
    f32x4 zz = {0.f, 0.f, 0.f, 0.f};
    for (int ct = 0; ct < 4; ct++) acc[ct] = zz;
#pragma unroll
    for (int ks = 0; ks < 4; ks++) {
      int arow = wm + r15;                     // p strip
      bf16x8 af = *(const bf16x8*)&Sb[arow * 128 + (((ks * 4 + quad) ^ (r15 & 7)) << 3)];
#pragma unroll
      for (int ct = 0; ct < 4; ct++) {
        int brow = ct * 16 + r15;              // l rows
        bf16x8 bfr = *(const bf16x8*)&Cb[brow * 128 + (((ks * 4 + quad) ^ (r15 & 7)) << 3)];
        acc[ct] = __builtin_amdgcn_mfma_f32_16x16x32_bf16(af, bfr, acc[ct], 0, 0, 0);
      }
    }
#pragma unroll
    for (int ct = 0; ct < 4; ct++) {
      int l = ct * 16 + r15;
      int p0 = wm + quad * 4;
      int pg = p0 >> 3;
      const bf16x4 yv = *(const bf16x4*)&Yt[l * 64 + ((pg ^ (l & 7)) << 3) + (p0 & 7)];
      float ao = aout[hh * 64 + l];
      bf16x4 r;
#pragma unroll
      for (int i = 0; i < 4; i++)
        r[i] = (__bf16)((float)yv[i] + ao * acc[ct][i]);
      *(bf16x4*)(y + (size_t)(base + l) * DIN + h * HD + p0) = r;
    }
    __syncthreads();   // before next head's staging overwrites Sb/Yt
  }
}

extern "C" void kernel_launch(void* const* d_in, const int* in_sizes, int n_in,
                              void* d_out, int out_size, void* d_ws, size_t ws_size,
                              hipStream_t stream) {
  const float* x       = (const float*)d_in[0];
  const float* in_w    = (const float*)d_in[1];
  const float* conv_w  = (const float*)d_in[2];
  const float* conv_b  = (const float*)d_in[3];
  const float* dt_bias = (const float*)d_in[4];
  const float* A_log   = (const float*)d_in[5];
  const float* Dp      = (const float*)d_in[6];
  const float* out_w   = (const float*)d_in[7];
  float* out = (float*)d_out;

  char* cur = (char*)d_ws;
  auto alloc = [&](size_t bytes) {
    char* p = cur;
    cur += (bytes + 255) & ~(size_t)255;
    return p;
  };
  __hip_bfloat16* xbc   = (__hip_bfloat16*)alloc((size_t)T_TOK * CONVD * 2);
  float* dtb            = (float*)alloc((size_t)T_TOK * NH * 4);
  float* acum           = (float*)alloc((size_t)T_TOK * NH * 4);
  float* echunk         = (float*)alloc((size_t)NBC * NH * 4);
  __hip_bfloat16* xh    = (__hip_bfloat16*)alloc((size_t)T_TOK * DIN * 2);
  __hip_bfloat16* Bm    = (__hip_bfloat16*)alloc((size_t)T_TOK * DSTATE * 2);
  __hip_bfloat16* Cm    = (__hip_bfloat16*)alloc((size_t)T_TOK * DSTATE * 2);
  __hip_bfloat16* ybuf  = (__hip_bfloat16*)alloc((size_t)T_TOK * DIN * 2);
  __hip_bfloat16* states= (__hip_bfloat16*)alloc((size_t)NBC * NH * HD * DSTATE * 2);
  __hip_bfloat16* wib   = (__hip_bfloat16*)alloc((size_t)NPAD * DM * 2);
  __hip_bfloat16* wob   = (__hip_bfloat16*)alloc((size_t)DIN * DM * 2);
  __hip_bfloat16* xb    = states;   // alias: xb dead before k_ssd1 writes states

  k_pre    <<<dim3(9312), 256, 0, stream>>>(x, xb, in_w, wib, out_w, wob);
  k_gemmp<DM, true, NPAD / 128><<<dim3((NPAD / 128) * (T_TOK / 128)), 256, 0, stream>>>(
      xb, wib, nullptr, xbc, dtb, dt_bias, 0);
  k_conv   <<<dim3(3, T_TOK), 256, 0, stream>>>(xbc, conv_w, conv_b, xh, Bm, Cm);
  k_ssd1   <<<dim3(NBC, 4),   256, 0, stream>>>(xh, Bm, Cm, dtb, A_log, Dp, ybuf, states, acum, echunk);
  k_scan   <<<dim3(512),      256, 0, stream>>>(states, echunk);
  k_ssd2   <<<dim3(NBC, 8),   256, 0, stream>>>(states, Cm, acum, ybuf);
  k_gemmp<DIN, false, DM / 128><<<dim3((DM / 128) * (T_TOK / 128)), 256, 0, stream>>>(
      ybuf, wob, out, nullptr, nullptr, nullptr, DM);
}

// Round 7
// 341.335 us; speedup vs baseline: 1.0087x; 1.0044x over previous
//
#include <hip/hip_runtime.h>
#include <hip/hip_bf16.h>
#include <math.h>
#include <stdint.h>

#define T_TOK 8192      // b*l
#define L_SEQ 4096
#define DM    1024
#define DIN   2048
#define DSTATE 128
#define NH    32
#define HD    64
#define CH    64        // chunk length
#define NCH   64        // chunks per batch
#define NBC   128       // B * NCH
#define CONVD 2304
#define NPROJ 2336      // columns of in_proj we actually need (z gate unused)
#define NPAD  2432      // NPROJ padded to multiple of 128
#define PROJ_OFF 2048
#define DPROJ 4384

typedef __bf16 bf16x8 __attribute__((ext_vector_type(8)));
typedef __bf16 bf16x4 __attribute__((ext_vector_type(4)));
typedef __bf16 bf16x2 __attribute__((ext_vector_type(2)));
typedef float f32x4 __attribute__((ext_vector_type(4)));

__device__ __forceinline__ void gload_lds16(const void* g, void* l) {
  __builtin_amdgcn_global_load_lds(
      (const __attribute__((address_space(1))) void*)(uintptr_t)g,
      (__attribute__((address_space(3))) void*)(uintptr_t)l, 16, 0, 0);
}

#define SCHEDB() __builtin_amdgcn_sched_barrier(0)
#define BARx()   __builtin_amdgcn_s_barrier()
#define LGKM0() do { asm volatile("s_waitcnt lgkmcnt(0)" ::: "memory"); SCHEDB(); } while (0)
#define VMC(N)  do { asm volatile("s_waitcnt vmcnt(" #N ")" ::: "memory"); SCHEDB(); } while (0)

// ---------------- K0: fused preprocessing: cast x + transpose both weights --
__global__ __launch_bounds__(256) void k_pre(const float* __restrict__ x,
    __hip_bfloat16* __restrict__ xb, const float* __restrict__ in_w,
    __hip_bfloat16* __restrict__ wib, const float* __restrict__ out_w,
    __hip_bfloat16* __restrict__ wob) {
  __shared__ float s[64][65];
  int bid = blockIdx.x;
  if (bid < 8192) {                       // cast x -> bf16
    int i = (bid * 256 + threadIdx.x) * 4;
    float4 v = *(const float4*)(x + i);
    bf16x4 r;
    r[0] = (__bf16)v.x; r[1] = (__bf16)v.y; r[2] = (__bf16)v.z; r[3] = (__bf16)v.w;
    *(bf16x4*)(xb + i) = r;
    return;
  }
  const float* w; __hip_bfloat16* wt;
  int K, ldsrc, colOff, ncols, kx, ny;
  if (bid < 8800) {                       // in_proj weight transpose
    int b2 = bid - 8192; kx = b2 & 15; ny = b2 >> 4;
    w = in_w; wt = wib; K = DM; ldsrc = DPROJ; colOff = PROJ_OFF; ncols = NPROJ;
  } else {                                // out_proj weight transpose
    int b3 = bid - 8800; kx = b3 & 31; ny = b3 >> 5;
    w = out_w; wt = wob; K = DIN; ldsrc = DM; colOff = 0; ncols = DM;
  }
  int k0 = kx * 64, n0 = ny * 64;
  int c = threadIdx.x & 63, r0 = threadIdx.x >> 6;
  for (int i = 0; i < 16; i++) {
    int r = r0 + 4 * i;
    int ng = n0 + c;
    s[r][c] = (ng < ncols) ? w[(size_t)(k0 + r) * ldsrc + colOff + ng] : 0.f;
  }
  __syncthreads();
  for (int i = 0; i < 16; i++) {
    int a = r0 + 4 * i;
    wt[(size_t)(n0 + a) * K + k0 + c] = __float2bfloat16(s[c][a]);
  }
}

// ---------------- MFMA GEMM (round-4 proven structure, 67 µs) --------------
// reads -> lgkm0 -> barrier -> stage(it+2) -> MFMA -> counted VMC -> barrier.
// vmcnt ledger (8 loads/stage, in-order):
//   steady (it < nIter-2): outstanding 16 -> VMC(8) drains stage(it-1)
//     which feeds iter it+1; this iter's 8 stay in flight.
//   it == nIter-2: stage skipped -> outstanding 8 = last buffer's loads
//     -> VMC(0) full drain.  it == nIter-1: nothing outstanding.
// (Round-5 A/B: other orderings regressed 67->75/78 µs. Local optimum of the
//  128² dbuf structure; do not re-perturb without new counter evidence.)
template <int KDIM, bool SPLIT, int NTN>
__global__ __launch_bounds__(256) void k_gemmp(
    const __hip_bfloat16* __restrict__ A, const __hip_bfloat16* __restrict__ Bt,
    float* __restrict__ C, __hip_bfloat16* __restrict__ Cb16,
    float* __restrict__ dtb, const float* __restrict__ dt_bias, int NLD) {
  __shared__ __attribute__((aligned(16))) __hip_bfloat16 sA[2][128 * 64];
  __shared__ __attribute__((aligned(16))) __hip_bfloat16 sB[2][128 * 64];
  int tid = threadIdx.x;
  int wid = tid >> 6, lane = tid & 63;
  // T1: bijective XCD swizzle (gridDim.x divisible by 8)
  int f = blockIdx.x;
  int wg = (f & 7) * ((int)gridDim.x >> 3) + (f >> 3);
  int t0 = (wg / NTN) * 128, n0 = (wg % NTN) * 128;
  int wm = (wid >> 1) * 64, wn = (wid & 1) * 64;
  int r15 = lane & 15, quad = lane >> 4;
  int srow = lane >> 3;
  int kcs = lane & 7;

  f32x4 acc[4][4];
  f32x4 zz = {0.f, 0.f, 0.f, 0.f};
  for (int ni = 0; ni < 4; ni++)
    for (int ti = 0; ti < 4; ti++) acc[ni][ti] = zz;

  const __hip_bfloat16* Abase = A + (size_t)t0 * KDIM;
  const __hip_bfloat16* Bbase = Bt + (size_t)n0 * KDIM;

  auto stage = [&](int bb, int k0) {
#pragma unroll
    for (int c = 0; c < 4; c++) {
      int R0 = (wid * 4 + c) * 8;
      int row = R0 + srow;
      int kcg = kcs ^ (row & 7);
      gload_lds16(Abase + (size_t)row * KDIM + k0 + kcg * 8, &sA[bb][R0 * 64]);
      gload_lds16(Bbase + (size_t)row * KDIM + k0 + kcg * 8, &sB[bb][R0 * 64]);
    }
  };

  // prologue: two tiles in flight; wait only for the first
  stage(0, 0);
  stage(1, 64);
  VMC(8);
  BARx(); SCHEDB();

  const int nIter = KDIM / 64;
  for (int it = 0; it < nIter; ++it) {
    const int bb = it & 1;
    // 1) whole current tile -> registers
    bf16x8 wf[4][2], xf[4][2];
#pragma unroll
    for (int s = 0; s < 2; s++) {
      int sw = ((s << 2) | quad) ^ (r15 & 7);
#pragma unroll
      for (int ni = 0; ni < 4; ni++)
        wf[ni][s] = *reinterpret_cast<const bf16x8*>(&sB[bb][(wn + ni * 16 + r15) * 64 + sw * 8]);
#pragma unroll
      for (int ti = 0; ti < 4; ti++)
        xf[ti][s] = *reinterpret_cast<const bf16x8*>(&sA[bb][(wm + ti * 16 + r15) * 64 + sw * 8]);
    }
    LGKM0();            // own ds_reads complete
    BARx(); SCHEDB();   // all waves' reads complete -> cur buffer reusable
    // 2) refill cur buffer for iteration it+2 (async, ~2-iter lead)
    if (it + 2 < nIter) stage(bb, (it + 2) * 64);
    // 3) compute from registers
#pragma unroll
    for (int s = 0; s < 2; s++)
#pragma unroll
      for (int ni = 0; ni < 4; ni++)
#pragma unroll
        for (int ti = 0; ti < 4; ti++)
          acc[ni][ti] = __builtin_amdgcn_mfma_f32_16x16x32_bf16(wf[ni][s], xf[ti][s], acc[ni][ti], 0, 0, 0);
    // 4) guard the next buffer's staging loads (see ledger above)
    if (it < nIter - 2) {
      VMC(8);
      BARx(); SCHEDB();
    } else if (it == nIter - 2) {
      VMC(0);                      // last buffer's loads: full drain
      BARx(); SCHEDB();
    }
    // it == nIter-1: fall through to epilogue, nothing outstanding
  }

  // epilogue: D[n = quad*4+i][t = r15], vector stores over n
#pragma unroll
  for (int ni = 0; ni < 4; ni++) {
    int n = n0 + wn + ni * 16 + quad * 4;
#pragma unroll
    for (int ti = 0; ti < 4; ti++) {
      int t = t0 + wm + ti * 16 + r15;
      f32x4 v = acc[ni][ti];
      if (SPLIT) {
        if (n < CONVD) {
          bf16x4 r;
#pragma unroll
          for (int i = 0; i < 4; i++) r[i] = (__bf16)v[i];
          *(bf16x4*)(Cb16 + (size_t)t * CONVD + n) = r;
        } else if (n < NPROJ) {     // [CONVD, NPROJ) — 4-aligned boundary
#pragma unroll
          for (int i = 0; i < 4; i++) {
            int h = n + i - CONVD;
            float z = v[i] + dt_bias[h];
            float sp = (z > 20.f) ? z : log1pf(__expf(z));
            dtb[t * NH + h] = sp;
          }
        }
        // n >= NPROJ: zero-padded columns, discarded
      } else {
        *(float4*)(C + (size_t)t * NLD + n) = *(float4*)&v;
      }
    }
  }
}

// ---------------- K2: depthwise causal conv(4) + bias + SiLU (4 ch/thread) --
__global__ __launch_bounds__(256) void k_conv(const __hip_bfloat16* __restrict__ xbc,
    const float* __restrict__ cw, const float* __restrict__ cb,
    __hip_bfloat16* __restrict__ xh, __hip_bfloat16* __restrict__ Bm,
    __hip_bfloat16* __restrict__ Cm) {
  int pi = blockIdx.x * 256 + threadIdx.x;
  if (pi >= CONVD / 4) return;
  int ch = pi * 4;
  int t = blockIdx.y;
  int l = t & (L_SEQ - 1);
  float4 cb4 = *(const float4*)(cb + ch);
  float acc[4] = {cb4.x, cb4.y, cb4.z, cb4.w};
#pragma unroll
  for (int j = 0; j < 4; j++) {
    int ls = l - 3 + j;
    if (ls >= 0) {
      bf16x4 v = *(const bf16x4*)(xbc + (size_t)(t - 3 + j) * CONVD + ch);
      float4 w4 = *(const float4*)(cw + j * CONVD + ch);
      acc[0] += (float)v[0] * w4.x;
      acc[1] += (float)v[1] * w4.y;
      acc[2] += (float)v[2] * w4.z;
      acc[3] += (float)v[3] * w4.w;
    }
  }
  bf16x4 r;
#pragma unroll
  for (int i = 0; i < 4; i++) {
    float sv = acc[i] / (1.f + __expf(-acc[i]));
    r[i] = (__bf16)sv;
  }
  if (ch < DIN)                 *(bf16x4*)(xh + (size_t)t * DIN + ch) = r;
  else if (ch < DIN + DSTATE)   *(bf16x4*)(Bm + (size_t)t * DSTATE + ch - DIN) = r;
  else                          *(bf16x4*)(Cm + (size_t)t * DSTATE + ch - DIN - DSTATE) = r;
}

// ---------------- K4: fused SSD per (chunk, 8 heads), acum folded in --------
// All transposed LDS arrays use stride-64 XOR-granule layout: element (row, k)
// stored at row*64 + ((k>>3)^(row&7))*8 + (k&7). Store/read swizzles cancel.
// Round-7: T14 async-stage split — next head's xh loads issued BEFORE the
// compute phase (P/Y/S ≈ 1500+ cyc) so HBM/L2 latency hides under MFMA work.
// (Round-6's operand-swap epilogues + extra barriers regressed; reverted.)
__global__ __launch_bounds__(256) void k_ssd1(
    const __hip_bfloat16* __restrict__ xh, const __hip_bfloat16* __restrict__ Bm,
    const __hip_bfloat16* __restrict__ Cm, const float* __restrict__ dtb,
    const float* __restrict__ A_log, const float* __restrict__ Dp,
    __hip_bfloat16* __restrict__ ypart, __hip_bfloat16* __restrict__ statesT,
    float* __restrict__ acum_out, float* __restrict__ echunk) {
  __shared__ __attribute__((aligned(16))) char smem[32768 + 8192 + 6144];
  __hip_bfloat16* Cb  = (__hip_bfloat16*)smem;            // 64x128 swz (phase 1)
  __hip_bfloat16* Bb  = Cb + 64 * 128;                    // 64x128 swz (phase 1)
  __hip_bfloat16* BT  = (__hip_bfloat16*)smem;            // 128x64 [n][l] (phase 2, alias)
  __hip_bfloat16* xdT = BT + 128 * 64;                    // 64x64 [p][l] x*dt
  __hip_bfloat16* xsT = xdT + 64 * 64;                    // 64x64 [p][l] x*dt*dec
  __hip_bfloat16* P   = (__hip_bfloat16*)(smem + 32768);  // 64x64 [l][s]
  float* acvA = (float*)(smem + 32768 + 8192);            // [8][64]
  float* dtsA = acvA + 512;
  float* decA = dtsA + 512;

  int bc = blockIdx.x, h0 = blockIdx.y * 8;
  int base = bc * CH;
  int tid = threadIdx.x, wid = tid >> 6, lane = tid & 63;
  int r15 = lane & 15, quad = lane >> 4;
  int wm = wid * 16;
  f32x4 zz = {0.f, 0.f, 0.f, 0.f};

  // stage Cb/Bb via async gload (row-granule XOR swizzle on global side)
  {
    int srow = lane >> 4, g = lane & 15;
    for (int c = 0; c < 4; c++) {
      int R0 = wid * 16 + c * 4;
      int r = R0 + srow;
      int gs = g ^ (r & 7);
      gload_lds16(Cm + (size_t)(base + r) * DSTATE + gs * 8, &Cb[R0 * DSTATE]);
      gload_lds16(Bm + (size_t)(base + r) * DSTATE + gs * 8, &Bb[R0 * DSTATE]);
    }
  }
  // preload dt (8 heads x 64 positions)
  for (int i = 0; i < 2; i++) {
    int idx = tid + 256 * i;
    int hh = idx >> 6, l = idx & 63;
    dtsA[hh * 64 + l] = dtb[(base + l) * NH + h0 + hh];
  }
  __syncthreads();
  // in-block cumsum of A*dt (one serial lane per head; 64 fp32 adds)
  if (tid < 8) {
    int h = h0 + tid;
    float a = -__expf(A_log[h]);
    float s = 0.f;
    for (int l = 0; l < CH; l++) {
      s += a * dtsA[tid * 64 + l];
      acvA[tid * 64 + l] = s;
    }
    echunk[bc * NH + h] = __expf(s);
  }
  __syncthreads();
  // dec + persist acum for k_ssd2
  for (int i = 0; i < 2; i++) {
    int idx = tid + 256 * i;
    int hh = idx >> 6, l = idx & 63;
    float a = acvA[hh * 64 + l];
    decA[hh * 64 + l] = __expf(acvA[hh * 64 + 63] - a);
    acum_out[(base + l) * NH + h0 + hh] = a;
  }

  // --- G = C.B^T once: wave strip rows wm..wm+15 x all 64 s (K=128)
  f32x4 accg[4];
  for (int ct = 0; ct < 4; ct++) accg[ct] = zz;
#pragma unroll
  for (int ks = 0; ks < 4; ks++) {
    int arow = wm + r15;
    bf16x8 af = *(const bf16x8*)&Cb[arow * 128 + (((ks * 4 + quad) ^ (r15 & 7)) << 3)];
#pragma unroll
    for (int ct = 0; ct < 4; ct++) {
      int brow = ct * 16 + r15;
      bf16x8 bfr = *(const bf16x8*)&Bb[brow * 128 + (((ks * 4 + quad) ^ (r15 & 7)) << 3)];
      accg[ct] = __builtin_amdgcn_mfma_f32_16x16x32_bf16(af, bfr, accg[ct], 0, 0, 0);
    }
  }
  __syncthreads();   // Cb/Bb dead; region reused below

  int l0 = (tid & 15) * 4;     // 4 consecutive l (same granule: l0%8 in {0,4})
  int q0 = tid >> 4;           // 0..15
  int go = l0 & 7;             // offset within granule
  int gl = l0 >> 3;            // true granule of l0
  int p0 = q0 * 4;             // 4 consecutive p per thread (xdT/xsT build)

  // T14 prologue: head 0's xh tile -> registers
  bf16x4 xpre[4];
#pragma unroll
  for (int dl = 0; dl < 4; dl++)
    xpre[dl] = *(const bf16x4*)(xh + (size_t)(base + l0 + dl) * DIN + h0 * HD + p0);

  for (int hh = 0; hh < 8; hh++) {
    int h = h0 + hh;
    if (hh == 0) {
      // build BT[n][l] once (head-independent, decay folded into xs)
      int n0 = q0 * 8;
      __bf16 tmp[8][4];
#pragma unroll
      for (int dl = 0; dl < 4; dl++) {
        bf16x8 bv = *(const bf16x8*)(Bm + (size_t)(base + l0 + dl) * DSTATE + n0);
#pragma unroll
        for (int dn = 0; dn < 8; dn++) tmp[dn][dl] = bv[dn];
      }
#pragma unroll
      for (int dn = 0; dn < 8; dn++) {
        int n = n0 + dn;
        bf16x4 pk = {tmp[dn][0], tmp[dn][1], tmp[dn][2], tmp[dn][3]};
        *(bf16x4*)&BT[n * 64 + ((gl ^ (n & 7)) << 3) + go] = pk;
      }
    }
    // build xdT (x*dt) and xsT (x*dt*dec) for this head from prefetched regs
    {
      __bf16 td[4][4], ts[4][4];
#pragma unroll
      for (int dl = 0; dl < 4; dl++) {
        int l = l0 + dl;
        bf16x4 xv = xpre[dl];
        float dt = dtsA[hh * 64 + l];
        float ds = dt * decA[hh * 64 + l];
#pragma unroll
        for (int dp = 0; dp < 4; dp++) {
          float xf = (float)xv[dp];
          td[dp][dl] = (__bf16)(xf * dt);
          ts[dp][dl] = (__bf16)(xf * ds);
        }
      }
#pragma unroll
      for (int dp = 0; dp < 4; dp++) {
        int p = p0 + dp;
        int off = p * 64 + ((gl ^ (p & 7)) << 3) + go;
        bf16x4 pd = {td[dp][0], td[dp][1], td[dp][2], td[dp][3]};
        bf16x4 ps = {ts[dp][0], ts[dp][1], ts[dp][2], ts[dp][3]};
        *(bf16x4*)&xdT[off] = pd;
        *(bf16x4*)&xsT[off] = ps;
      }
    }
    __syncthreads();

    // T14: issue NEXT head's xh loads now — they retire during the ~1500-cyc
    // compute phase below; waitcnt lands at first use (next iteration).
    bf16x4 xnxt[4];
    if (hh < 7) {
#pragma unroll
      for (int dl = 0; dl < 4; dl++)
        xnxt[dl] = *(const bf16x4*)(xh + (size_t)(base + l0 + dl) * DIN + (h + 1) * HD + p0);
    }

    // --- P = mask(G * decay) -> LDS (wave-private rows wm..wm+15)
#pragma unroll
    for (int ct = 0; ct < 4; ct++) {
      int s = ct * 16 + r15;
      float as = acvA[hh * 64 + s];
#pragma unroll
      for (int i = 0; i < 4; i++) {
        int l = wm + quad * 4 + i;
        float pv = (s <= l) ? accg[ct][i] * __expf(acvA[hh * 64 + l] - as) : 0.f;
        P[l * 64 + (((s >> 3) ^ (l & 7)) << 3) + (s & 7)] = __float2bfloat16(pv);
      }
    }
    // --- Y_diag = P.xd (K=64) + xh*D
    f32x4 accy[4];
    for (int ct = 0; ct < 4; ct++) accy[ct] = zz;
#pragma unroll
    for (int ks = 0; ks < 2; ks++) {
      int arow = wm + r15;
      bf16x8 af = *(const bf16x8*)&P[arow * 64 + (((ks * 4 + quad) ^ (r15 & 7)) << 3)];
#pragma unroll
      for (int ct = 0; ct < 4; ct++) {
        int brow = ct * 16 + r15;
        bf16x8 bfr = *(const bf16x8*)&xdT[brow * 64 + (((ks * 4 + quad) ^ (r15 & 7)) << 3)];
        accy[ct] = __builtin_amdgcn_mfma_f32_16x16x32_bf16(af, bfr, accy[ct], 0, 0, 0);
      }
    }
    float Dh = Dp[h];
#pragma unroll
    for (int ct = 0; ct < 4; ct++) {
      int p = ct * 16 + r15;
#pragma unroll
      for (int i = 0; i < 4; i++) {
        int l = wm + quad * 4 + i;
        float xv = __bfloat162float(xh[(size_t)(base + l) * DIN + h * HD + p]);
        ypart[(size_t)(base + l) * DIN + h * HD + p] = __float2bfloat16(accy[ct][i] + xv * Dh);
      }
    }
    // --- S^T[p][n] = sum_l xs[l][p] * B[l][n]  (K=64, wave strip over p)
    f32x4 accs[8];
    for (int ct = 0; ct < 8; ct++) accs[ct] = zz;
#pragma unroll
    for (int ks = 0; ks < 2; ks++) {
      int arow = wm + r15;   // p row
      bf16x8 af = *(const bf16x8*)&xsT[arow * 64 + (((ks * 4 + quad) ^ (r15 & 7)) << 3)];
#pragma unroll
      for (int ct = 0; ct < 8; ct++) {
        int brow = ct * 16 + r15;   // n row
        bf16x8 bfr = *(const bf16x8*)&BT[brow * 64 + (((ks * 4 + quad) ^ (r15 & 7)) << 3)];
        accs[ct] = __builtin_amdgcn_mfma_f32_16x16x32_bf16(af, bfr, accs[ct], 0, 0, 0);
      }
    }
    size_t sbase = ((size_t)bc * NH + h) * (HD * DSTATE);
#pragma unroll
    for (int ct = 0; ct < 8; ct++) {
      int n = ct * 16 + r15;
#pragma unroll
      for (int i = 0; i < 4; i++) {
        int p = wm + quad * 4 + i;
        statesT[sbase + (size_t)p * DSTATE + n] = __float2bfloat16(accs[ct][i]);
      }
    }
    __syncthreads();   // before next head overwrites xdT/xsT
#pragma unroll
    for (int dl = 0; dl < 4; dl++) xpre[dl] = xnxt[dl];
  }
}

// ---------------- K5: inter-chunk scan (in-place, 2 elems/thread) ----------
__global__ __launch_bounds__(256) void k_scan(__hip_bfloat16* __restrict__ states,
    const float* __restrict__ echunk) {
  int idx = blockIdx.x * 256 + threadIdx.x;   // 262144
  int inner = (idx & 4095) * 2;    // p*128+n, pair-aligned
  int h = (idx >> 12) & 31;
  int b = idx >> 17;
  float run0 = 0.f, run1 = 0.f;
  for (int c = 0; c < NCH; c++) {
    int bc = b * NCH + c;
    size_t off = ((size_t)bc * NH + h) * 8192 + inner;
    bf16x2 v = *(bf16x2*)(states + off);
    bf16x2 w = {(__bf16)run0, (__bf16)run1};
    *(bf16x2*)(states + off) = w;
    float e = echunk[bc * NH + h];
    run0 = run0 * e + (float)v[0];
    run1 = run1 * e + (float)v[1];
  }
}

// ---------------- K6: y += exp(acum)*(C.S_in^T), 4 heads/block, C reused ---
__global__ __launch_bounds__(256) void k_ssd2(
    const __hip_bfloat16* __restrict__ statesT, const __hip_bfloat16* __restrict__ Cm,
    const float* __restrict__ acum, __hip_bfloat16* __restrict__ y) {
  __shared__ __attribute__((aligned(16))) __hip_bfloat16 Cb[64 * 128];  // [l][n] swz
  __shared__ __attribute__((aligned(16))) __hip_bfloat16 Sb[64 * 128];  // [p][n] swz
  __shared__ __attribute__((aligned(16))) __hip_bfloat16 Yt[64 * 64];   // [l][p]
  __shared__ float aout[4 * 64];
  int bc = blockIdx.x, h0 = blockIdx.y * 4;
  int base = bc * CH;
  int tid = threadIdx.x, wid = tid >> 6, lane = tid & 63;
  int r15 = lane & 15, quad = lane >> 4;
  int wm = wid * 16;
  int srow = lane >> 4, g = lane & 15;

  aout[tid] = __expf(acum[(base + (tid & 63)) * NH + h0 + (tid >> 6)]);
  // stage Cb once (reused for all 4 heads)
  for (int c = 0; c < 4; c++) {
    int R0 = wid * 16 + c * 4;
    int r = R0 + srow;
    int gs = g ^ (r & 7);
    gload_lds16(Cm + (size_t)(base + r) * DSTATE + gs * 8, &Cb[R0 * DSTATE]);
  }

  for (int hh = 0; hh < 4; hh++) {
    int h = h0 + hh;
    size_t sbase = ((size_t)bc * NH + h) * (HD * DSTATE);
    // stage Sb + Yt for this head
    for (int c = 0; c < 4; c++) {
      int R0 = wid * 16 + c * 4;
      int r = R0 + srow;
      int gs = g ^ (r & 7);
      gload_lds16(statesT + sbase + (size_t)r * DSTATE + gs * 8, &Sb[R0 * DSTATE]);
    }
    for (int c = 0; c < 2; c++) {
      int R0 = wid * 16 + c * 8;
      int r = R0 + (lane >> 3);
      gload_lds16(y + (size_t)(base + r) * DIN + h * HD + (lane & 7) * 8, &Yt[R0 * 64]);
    }
    __syncthreads();

    f32x4 acc[4];
    f32x4 zz = {0.f, 0.f, 0.f, 0.f};
    for (int ct = 0; ct < 4; ct++) acc[ct] = zz;
#pragma unroll
    for (int ks = 0; ks < 4; ks++) {
      int arow = wm + r15;
      bf16x8 af = *(const bf16x8*)&Cb[arow * 128 + (((ks * 4 + quad) ^ (r15 & 7)) << 3)];
#pragma unroll
      for (int ct = 0; ct < 4; ct++) {
        int brow = ct * 16 + r15;
        bf16x8 bfr = *(const bf16x8*)&Sb[brow * 128 + (((ks * 4 + quad) ^ (r15 & 7)) << 3)];
        acc[ct] = __builtin_amdgcn_mfma_f32_16x16x32_bf16(af, bfr, acc[ct], 0, 0, 0);
      }
    }
#pragma unroll
    for (int ct = 0; ct < 4; ct++) {
      int p = ct * 16 + r15;
#pragma unroll
      for (int i = 0; i < 4; i++) {
        int l = wm + quad * 4 + i;
        float v = __bfloat162float(Yt[l * 64 + p]) + aout[hh * 64 + l] * acc[ct][i];
        y[(size_t)(base + l) * DIN + h * HD + p] = __float2bfloat16(v);
      }
    }
    __syncthreads();   // before next head's staging overwrites Sb/Yt
  }
}

extern "C" void kernel_launch(void* const* d_in, const int* in_sizes, int n_in,
                              void* d_out, int out_size, void* d_ws, size_t ws_size,
                              hipStream_t stream) {
  const float* x       = (const float*)d_in[0];
  const float* in_w    = (const float*)d_in[1];
  const float* conv_w  = (const float*)d_in[2];
  const float* conv_b  = (const float*)d_in[3];
  const float* dt_bias = (const float*)d_in[4];
  const float* A_log   = (const float*)d_in[5];
  const float* Dp      = (const float*)d_in[6];
  const float* out_w   = (const float*)d_in[7];
  float* out = (float*)d_out;

  char* cur = (char*)d_ws;
  auto alloc = [&](size_t bytes) {
    char* p = cur;
    cur += (bytes + 255) & ~(size_t)255;
    return p;
  };
  __hip_bfloat16* xbc   = (__hip_bfloat16*)alloc((size_t)T_TOK * CONVD * 2);
  float* dtb            = (float*)alloc((size_t)T_TOK * NH * 4);
  float* acum           = (float*)alloc((size_t)T_TOK * NH * 4);
  float* echunk         = (float*)alloc((size_t)NBC * NH * 4);
  __hip_bfloat16* xh    = (__hip_bfloat16*)alloc((size_t)T_TOK * DIN * 2);
  __hip_bfloat16* Bm    = (__hip_bfloat16*)alloc((size_t)T_TOK * DSTATE * 2);
  __hip_bfloat16* Cm    = (__hip_bfloat16*)alloc((size_t)T_TOK * DSTATE * 2);
  __hip_bfloat16* ybuf  = (__hip_bfloat16*)alloc((size_t)T_TOK * DIN * 2);
  __hip_bfloat16* states= (__hip_bfloat16*)alloc((size_t)NBC * NH * HD * DSTATE * 2);
  __hip_bfloat16* wib   = (__hip_bfloat16*)alloc((size_t)NPAD * DM * 2);
  __hip_bfloat16* wob   = (__hip_bfloat16*)alloc((size_t)DIN * DM * 2);
  __hip_bfloat16* xb    = states;   // alias: xb dead before k_ssd1 writes states

  k_pre    <<<dim3(9312), 256, 0, stream>>>(x, xb, in_w, wib, out_w, wob);
  k_gemmp<DM, true, NPAD / 128><<<dim3((NPAD / 128) * (T_TOK / 128)), 256, 0, stream>>>(
      xb, wib, nullptr, xbc, dtb, dt_bias, 0);
  k_conv   <<<dim3(3, T_TOK), 256, 0, stream>>>(xbc, conv_w, conv_b, xh, Bm, Cm);
  k_ssd1   <<<dim3(NBC, 4),   256, 0, stream>>>(xh, Bm, Cm, dtb, A_log, Dp, ybuf, states, acum, echunk);
  k_scan   <<<dim3(1024),     256, 0, stream>>>(states, echunk);
  k_ssd2   <<<dim3(NBC, 8),   256, 0, stream>>>(states, Cm, acum, ybuf);
  k_gemmp<DIN, false, DM / 128><<<dim3((DM / 128) * (T_TOK / 128)), 256, 0, stream>>>(
      ybuf, wob, out, nullptr, nullptr, nullptr, DM);
}

// Round 8
// 336.342 us; speedup vs baseline: 1.0237x; 1.0148x over previous
//
#include <hip/hip_runtime.h>
#include <hip/hip_bf16.h>
#include <math.h>
#include <stdint.h>

#define T_TOK 8192      // b*l
#define L_SEQ 4096
#define DM    1024
#define DIN   2048
#define DSTATE 128
#define NH    32
#define HD    64
#define CH    64        // chunk length
#define NCH   64        // chunks per batch
#define NBC   128       // B * NCH
#define CONVD 2304
#define NPROJ 2336      // columns of in_proj we actually need (z gate unused)
#define NPAD  2432      // NPROJ padded to multiple of 128
#define PROJ_OFF 2048
#define DPROJ 4384

typedef __bf16 bf16x8 __attribute__((ext_vector_type(8)));
typedef __bf16 bf16x4 __attribute__((ext_vector_type(4)));
typedef __bf16 bf16x2 __attribute__((ext_vector_type(2)));
typedef float f32x4 __attribute__((ext_vector_type(4)));

__device__ __forceinline__ void gload_lds16(const void* g, void* l) {
  __builtin_amdgcn_global_load_lds(
      (const __attribute__((address_space(1))) void*)(uintptr_t)g,
      (__attribute__((address_space(3))) void*)(uintptr_t)l, 16, 0, 0);
}

#define SCHEDB() __builtin_amdgcn_sched_barrier(0)
#define BARx()   __builtin_amdgcn_s_barrier()
#define LGKM0() do { asm volatile("s_waitcnt lgkmcnt(0)" ::: "memory"); SCHEDB(); } while (0)
#define VMC(N)  do { asm volatile("s_waitcnt vmcnt(" #N ")" ::: "memory"); SCHEDB(); } while (0)

// ---------------- K0: fused preprocessing: cast x + transpose both weights --
__global__ __launch_bounds__(256) void k_pre(const float* __restrict__ x,
    __hip_bfloat16* __restrict__ xb, const float* __restrict__ in_w,
    __hip_bfloat16* __restrict__ wib, const float* __restrict__ out_w,
    __hip_bfloat16* __restrict__ wob) {
  __shared__ float s[64][65];
  int bid = blockIdx.x;
  if (bid < 8192) {                       // cast x -> bf16
    int i = (bid * 256 + threadIdx.x) * 4;
    float4 v = *(const float4*)(x + i);
    bf16x4 r;
    r[0] = (__bf16)v.x; r[1] = (__bf16)v.y; r[2] = (__bf16)v.z; r[3] = (__bf16)v.w;
    *(bf16x4*)(xb + i) = r;
    return;
  }
  const float* w; __hip_bfloat16* wt;
  int K, ldsrc, colOff, ncols, kx, ny;
  if (bid < 8800) {                       // in_proj weight transpose
    int b2 = bid - 8192; kx = b2 & 15; ny = b2 >> 4;
    w = in_w; wt = wib; K = DM; ldsrc = DPROJ; colOff = PROJ_OFF; ncols = NPROJ;
  } else {                                // out_proj weight transpose
    int b3 = bid - 8800; kx = b3 & 31; ny = b3 >> 5;
    w = out_w; wt = wob; K = DIN; ldsrc = DM; colOff = 0; ncols = DM;
  }
  int k0 = kx * 64, n0 = ny * 64;
  int c = threadIdx.x & 63, r0 = threadIdx.x >> 6;
  for (int i = 0; i < 16; i++) {
    int r = r0 + 4 * i;
    int ng = n0 + c;
    s[r][c] = (ng < ncols) ? w[(size_t)(k0 + r) * ldsrc + colOff + ng] : 0.f;
  }
  __syncthreads();
  for (int i = 0; i < 16; i++) {
    int a = r0 + 4 * i;
    wt[(size_t)(n0 + a) * K + k0 + c] = __float2bfloat16(s[c][a]);
  }
}

// ---------------- MFMA GEMM (round-4 proven structure, 67 µs) --------------
// reads -> lgkm0 -> barrier -> stage(it+2) -> MFMA -> counted VMC -> barrier.
// vmcnt ledger (8 loads/stage, in-order):
//   steady (it < nIter-2): outstanding 16 -> VMC(8) drains stage(it-1)
//     which feeds iter it+1; this iter's 8 stay in flight.
//   it == nIter-2: stage skipped -> outstanding 8 = last buffer's loads
//     -> VMC(0) full drain.  it == nIter-1: nothing outstanding.
// (Round-5 A/B: other orderings regressed 67->75/78 µs. Local optimum of the
//  128² dbuf structure; do not re-perturb without new counter evidence.)
template <int KDIM, bool SPLIT, int NTN>
__global__ __launch_bounds__(256) void k_gemmp(
    const __hip_bfloat16* __restrict__ A, const __hip_bfloat16* __restrict__ Bt,
    float* __restrict__ C, __hip_bfloat16* __restrict__ Cb16,
    float* __restrict__ dtb, const float* __restrict__ dt_bias, int NLD) {
  __shared__ __attribute__((aligned(16))) __hip_bfloat16 sA[2][128 * 64];
  __shared__ __attribute__((aligned(16))) __hip_bfloat16 sB[2][128 * 64];
  int tid = threadIdx.x;
  int wid = tid >> 6, lane = tid & 63;
  // T1: bijective XCD swizzle (gridDim.x divisible by 8)
  int f = blockIdx.x;
  int wg = (f & 7) * ((int)gridDim.x >> 3) + (f >> 3);
  int t0 = (wg / NTN) * 128, n0 = (wg % NTN) * 128;
  int wm = (wid >> 1) * 64, wn = (wid & 1) * 64;
  int r15 = lane & 15, quad = lane >> 4;
  int srow = lane >> 3;
  int kcs = lane & 7;

  f32x4 acc[4][4];
  f32x4 zz = {0.f, 0.f, 0.f, 0.f};
  for (int ni = 0; ni < 4; ni++)
    for (int ti = 0; ti < 4; ti++) acc[ni][ti] = zz;

  const __hip_bfloat16* Abase = A + (size_t)t0 * KDIM;
  const __hip_bfloat16* Bbase = Bt + (size_t)n0 * KDIM;

  auto stage = [&](int bb, int k0) {
#pragma unroll
    for (int c = 0; c < 4; c++) {
      int R0 = (wid * 4 + c) * 8;
      int row = R0 + srow;
      int kcg = kcs ^ (row & 7);
      gload_lds16(Abase + (size_t)row * KDIM + k0 + kcg * 8, &sA[bb][R0 * 64]);
      gload_lds16(Bbase + (size_t)row * KDIM + k0 + kcg * 8, &sB[bb][R0 * 64]);
    }
  };

  // prologue: two tiles in flight; wait only for the first
  stage(0, 0);
  stage(1, 64);
  VMC(8);
  BARx(); SCHEDB();

  const int nIter = KDIM / 64;
  for (int it = 0; it < nIter; ++it) {
    const int bb = it & 1;
    // 1) whole current tile -> registers
    bf16x8 wf[4][2], xf[4][2];
#pragma unroll
    for (int s = 0; s < 2; s++) {
      int sw = ((s << 2) | quad) ^ (r15 & 7);
#pragma unroll
      for (int ni = 0; ni < 4; ni++)
        wf[ni][s] = *reinterpret_cast<const bf16x8*>(&sB[bb][(wn + ni * 16 + r15) * 64 + sw * 8]);
#pragma unroll
      for (int ti = 0; ti < 4; ti++)
        xf[ti][s] = *reinterpret_cast<const bf16x8*>(&sA[bb][(wm + ti * 16 + r15) * 64 + sw * 8]);
    }
    LGKM0();            // own ds_reads complete
    BARx(); SCHEDB();   // all waves' reads complete -> cur buffer reusable
    // 2) refill cur buffer for iteration it+2 (async, ~2-iter lead)
    if (it + 2 < nIter) stage(bb, (it + 2) * 64);
    // 3) compute from registers
#pragma unroll
    for (int s = 0; s < 2; s++)
#pragma unroll
      for (int ni = 0; ni < 4; ni++)
#pragma unroll
        for (int ti = 0; ti < 4; ti++)
          acc[ni][ti] = __builtin_amdgcn_mfma_f32_16x16x32_bf16(wf[ni][s], xf[ti][s], acc[ni][ti], 0, 0, 0);
    // 4) guard the next buffer's staging loads (see ledger above)
    if (it < nIter - 2) {
      VMC(8);
      BARx(); SCHEDB();
    } else if (it == nIter - 2) {
      VMC(0);                      // last buffer's loads: full drain
      BARx(); SCHEDB();
    }
    // it == nIter-1: fall through to epilogue, nothing outstanding
  }

  // epilogue: D[n = quad*4+i][t = r15], vector stores over n
#pragma unroll
  for (int ni = 0; ni < 4; ni++) {
    int n = n0 + wn + ni * 16 + quad * 4;
#pragma unroll
    for (int ti = 0; ti < 4; ti++) {
      int t = t0 + wm + ti * 16 + r15;
      f32x4 v = acc[ni][ti];
      if (SPLIT) {
        if (n < CONVD) {
          bf16x4 r;
#pragma unroll
          for (int i = 0; i < 4; i++) r[i] = (__bf16)v[i];
          *(bf16x4*)(Cb16 + (size_t)t * CONVD + n) = r;
        } else if (n < NPROJ) {     // [CONVD, NPROJ) — 4-aligned boundary
#pragma unroll
          for (int i = 0; i < 4; i++) {
            int h = n + i - CONVD;
            float z = v[i] + dt_bias[h];
            float sp = (z > 20.f) ? z : log1pf(__expf(z));
            dtb[t * NH + h] = sp;
          }
        }
        // n >= NPROJ: zero-padded columns, discarded
      } else {
        *(float4*)(C + (size_t)t * NLD + n) = *(float4*)&v;
      }
    }
  }
}

// ---------------- K2: depthwise causal conv(4) + bias + SiLU (4 ch/thread) --
__global__ __launch_bounds__(256) void k_conv(const __hip_bfloat16* __restrict__ xbc,
    const float* __restrict__ cw, const float* __restrict__ cb,
    __hip_bfloat16* __restrict__ xh, __hip_bfloat16* __restrict__ Bm,
    __hip_bfloat16* __restrict__ Cm) {
  int pi = blockIdx.x * 256 + threadIdx.x;
  if (pi >= CONVD / 4) return;
  int ch = pi * 4;
  int t = blockIdx.y;
  int l = t & (L_SEQ - 1);
  float4 cb4 = *(const float4*)(cb + ch);
  float acc[4] = {cb4.x, cb4.y, cb4.z, cb4.w};
#pragma unroll
  for (int j = 0; j < 4; j++) {
    int ls = l - 3 + j;
    if (ls >= 0) {
      bf16x4 v = *(const bf16x4*)(xbc + (size_t)(t - 3 + j) * CONVD + ch);
      float4 w4 = *(const float4*)(cw + j * CONVD + ch);
      acc[0] += (float)v[0] * w4.x;
      acc[1] += (float)v[1] * w4.y;
      acc[2] += (float)v[2] * w4.z;
      acc[3] += (float)v[3] * w4.w;
    }
  }
  bf16x4 r;
#pragma unroll
  for (int i = 0; i < 4; i++) {
    float sv = acc[i] / (1.f + __expf(-acc[i]));
    r[i] = (__bf16)sv;
  }
  if (ch < DIN)                 *(bf16x4*)(xh + (size_t)t * DIN + ch) = r;
  else if (ch < DIN + DSTATE)   *(bf16x4*)(Bm + (size_t)t * DSTATE + ch - DIN) = r;
  else                          *(bf16x4*)(Cm + (size_t)t * DSTATE + ch - DIN - DSTATE) = r;
}

// ---------------- K4: fused SSD per (chunk, 8 heads), acum folded in --------
// All transposed LDS arrays use stride-64 XOR-granule layout: element (row, k)
// stored at row*64 + ((k>>3)^(row&7))*8 + (k&7). Store/read swizzles cancel.
// Round-8: ONLY the S^T operand swap is applied (vector statesT stores, no
// extra barrier — BT/xsT already block-shared+synced). Y_diag epilogue and
// everything else is the round-4 body (R6 bundle and R7 T14 both regressed).
__global__ __launch_bounds__(256) void k_ssd1(
    const __hip_bfloat16* __restrict__ xh, const __hip_bfloat16* __restrict__ Bm,
    const __hip_bfloat16* __restrict__ Cm, const float* __restrict__ dtb,
    const float* __restrict__ A_log, const float* __restrict__ Dp,
    __hip_bfloat16* __restrict__ ypart, __hip_bfloat16* __restrict__ statesT,
    float* __restrict__ acum_out, float* __restrict__ echunk) {
  __shared__ __attribute__((aligned(16))) char smem[32768 + 8192 + 6144];
  __hip_bfloat16* Cb  = (__hip_bfloat16*)smem;            // 64x128 swz (phase 1)
  __hip_bfloat16* Bb  = Cb + 64 * 128;                    // 64x128 swz (phase 1)
  __hip_bfloat16* BT  = (__hip_bfloat16*)smem;            // 128x64 [n][l] (phase 2, alias)
  __hip_bfloat16* xdT = BT + 128 * 64;                    // 64x64 [p][l] x*dt
  __hip_bfloat16* xsT = xdT + 64 * 64;                    // 64x64 [p][l] x*dt*dec
  __hip_bfloat16* P   = (__hip_bfloat16*)(smem + 32768);  // 64x64 [l][s]
  float* acvA = (float*)(smem + 32768 + 8192);            // [8][64]
  float* dtsA = acvA + 512;
  float* decA = dtsA + 512;

  int bc = blockIdx.x, h0 = blockIdx.y * 8;
  int base = bc * CH;
  int tid = threadIdx.x, wid = tid >> 6, lane = tid & 63;
  int r15 = lane & 15, quad = lane >> 4;
  int wm = wid * 16;
  f32x4 zz = {0.f, 0.f, 0.f, 0.f};

  // stage Cb/Bb via async gload (row-granule XOR swizzle on global side)
  {
    int srow = lane >> 4, g = lane & 15;
    for (int c = 0; c < 4; c++) {
      int R0 = wid * 16 + c * 4;
      int r = R0 + srow;
      int gs = g ^ (r & 7);
      gload_lds16(Cm + (size_t)(base + r) * DSTATE + gs * 8, &Cb[R0 * DSTATE]);
      gload_lds16(Bm + (size_t)(base + r) * DSTATE + gs * 8, &Bb[R0 * DSTATE]);
    }
  }
  // preload dt (8 heads x 64 positions)
  for (int i = 0; i < 2; i++) {
    int idx = tid + 256 * i;
    int hh = idx >> 6, l = idx & 63;
    dtsA[hh * 64 + l] = dtb[(base + l) * NH + h0 + hh];
  }
  __syncthreads();
  // in-block cumsum of A*dt (one serial lane per head; 64 fp32 adds)
  if (tid < 8) {
    int h = h0 + tid;
    float a = -__expf(A_log[h]);
    float s = 0.f;
    for (int l = 0; l < CH; l++) {
      s += a * dtsA[tid * 64 + l];
      acvA[tid * 64 + l] = s;
    }
    echunk[bc * NH + h] = __expf(s);
  }
  __syncthreads();
  // dec + persist acum for k_ssd2
  for (int i = 0; i < 2; i++) {
    int idx = tid + 256 * i;
    int hh = idx >> 6, l = idx & 63;
    float a = acvA[hh * 64 + l];
    decA[hh * 64 + l] = __expf(acvA[hh * 64 + 63] - a);
    acum_out[(base + l) * NH + h0 + hh] = a;
  }

  // --- G = C.B^T once: wave strip rows wm..wm+15 x all 64 s (K=128)
  f32x4 accg[4];
  for (int ct = 0; ct < 4; ct++) accg[ct] = zz;
#pragma unroll
  for (int ks = 0; ks < 4; ks++) {
    int arow = wm + r15;
    bf16x8 af = *(const bf16x8*)&Cb[arow * 128 + (((ks * 4 + quad) ^ (r15 & 7)) << 3)];
#pragma unroll
    for (int ct = 0; ct < 4; ct++) {
      int brow = ct * 16 + r15;
      bf16x8 bfr = *(const bf16x8*)&Bb[brow * 128 + (((ks * 4 + quad) ^ (r15 & 7)) << 3)];
      accg[ct] = __builtin_amdgcn_mfma_f32_16x16x32_bf16(af, bfr, accg[ct], 0, 0, 0);
    }
  }
  __syncthreads();   // Cb/Bb dead; region reused below

  int l0 = (tid & 15) * 4;     // 4 consecutive l (same granule: l0%8 in {0,4})
  int q0 = tid >> 4;           // 0..15
  int go = l0 & 7;             // offset within granule
  int gl = l0 >> 3;            // true granule of l0

  for (int hh = 0; hh < 8; hh++) {
    int h = h0 + hh;
    if (hh == 0) {
      // build BT[n][l] once (head-independent, decay folded into xs)
      int n0 = q0 * 8;
      __bf16 tmp[8][4];
#pragma unroll
      for (int dl = 0; dl < 4; dl++) {
        bf16x8 bv = *(const bf16x8*)(Bm + (size_t)(base + l0 + dl) * DSTATE + n0);
#pragma unroll
        for (int dn = 0; dn < 8; dn++) tmp[dn][dl] = bv[dn];
      }
#pragma unroll
      for (int dn = 0; dn < 8; dn++) {
        int n = n0 + dn;
        bf16x4 pk = {tmp[dn][0], tmp[dn][1], tmp[dn][2], tmp[dn][3]};
        *(bf16x4*)&BT[n * 64 + ((gl ^ (n & 7)) << 3) + go] = pk;
      }
    }
    // build xdT (x*dt) and xsT (x*dt*dec) for this head: 4l x 4p per thread
    {
      int p0 = q0 * 4;
      __bf16 td[4][4], ts[4][4];
#pragma unroll
      for (int dl = 0; dl < 4; dl++) {
        int l = l0 + dl;
        bf16x4 xv = *(const bf16x4*)(xh + (size_t)(base + l) * DIN + h * HD + p0);
        float dt = dtsA[hh * 64 + l];
        float ds = dt * decA[hh * 64 + l];
#pragma unroll
        for (int dp = 0; dp < 4; dp++) {
          float xf = (float)xv[dp];
          td[dp][dl] = (__bf16)(xf * dt);
          ts[dp][dl] = (__bf16)(xf * ds);
        }
      }
#pragma unroll
      for (int dp = 0; dp < 4; dp++) {
        int p = p0 + dp;
        int off = p * 64 + ((gl ^ (p & 7)) << 3) + go;
        bf16x4 pd = {td[dp][0], td[dp][1], td[dp][2], td[dp][3]};
        bf16x4 ps = {ts[dp][0], ts[dp][1], ts[dp][2], ts[dp][3]};
        *(bf16x4*)&xdT[off] = pd;
        *(bf16x4*)&xsT[off] = ps;
      }
    }
    __syncthreads();

    // --- P = mask(G * decay) -> LDS (wave-private rows wm..wm+15)
#pragma unroll
    for (int ct = 0; ct < 4; ct++) {
      int s = ct * 16 + r15;
      float as = acvA[hh * 64 + s];
#pragma unroll
      for (int i = 0; i < 4; i++) {
        int l = wm + quad * 4 + i;
        float pv = (s <= l) ? accg[ct][i] * __expf(acvA[hh * 64 + l] - as) : 0.f;
        P[l * 64 + (((s >> 3) ^ (l & 7)) << 3) + (s & 7)] = __float2bfloat16(pv);
      }
    }
    // --- Y_diag = P.xd (K=64) + xh*D   (round-4 body, wave-private P rows)
    f32x4 accy[4];
    for (int ct = 0; ct < 4; ct++) accy[ct] = zz;
#pragma unroll
    for (int ks = 0; ks < 2; ks++) {
      int arow = wm + r15;
      bf16x8 af = *(const bf16x8*)&P[arow * 64 + (((ks * 4 + quad) ^ (r15 & 7)) << 3)];
#pragma unroll
      for (int ct = 0; ct < 4; ct++) {
        int brow = ct * 16 + r15;
        bf16x8 bfr = *(const bf16x8*)&xdT[brow * 64 + (((ks * 4 + quad) ^ (r15 & 7)) << 3)];
        accy[ct] = __builtin_amdgcn_mfma_f32_16x16x32_bf16(af, bfr, accy[ct], 0, 0, 0);
      }
    }
    float Dh = Dp[h];
#pragma unroll
    for (int ct = 0; ct < 4; ct++) {
      int p = ct * 16 + r15;
#pragma unroll
      for (int i = 0; i < 4; i++) {
        int l = wm + quad * 4 + i;
        float xv = __bfloat162float(xh[(size_t)(base + l) * DIN + h * HD + p]);
        ypart[(size_t)(base + l) * DIN + h * HD + p] = __float2bfloat16(accy[ct][i] + xv * Dh);
      }
    }
    // --- S^T via operand swap: out n = hs*64+wm+quad*4+i, p = ct*16+r15
    // (BT/xsT already synced; no extra barrier. 18->12 LDS reads, 32 scalar
    //  -> 8 bf16x4 statesT stores per thread.)
    f32x4 accs[2][4];
    for (int hs = 0; hs < 2; hs++)
      for (int ct = 0; ct < 4; ct++) accs[hs][ct] = zz;
#pragma unroll
    for (int ks = 0; ks < 2; ks++) {
#pragma unroll
      for (int hs = 0; hs < 2; hs++) {
        int arow = hs * 64 + wm + r15;   // n strip
        bf16x8 af = *(const bf16x8*)&BT[arow * 64 + (((ks * 4 + quad) ^ (r15 & 7)) << 3)];
#pragma unroll
        for (int ct = 0; ct < 4; ct++) {
          int brow = ct * 16 + r15;      // p rows
          bf16x8 bfr = *(const bf16x8*)&xsT[brow * 64 + (((ks * 4 + quad) ^ (r15 & 7)) << 3)];
          accs[hs][ct] = __builtin_amdgcn_mfma_f32_16x16x32_bf16(af, bfr, accs[hs][ct], 0, 0, 0);
        }
      }
    }
    size_t sbase = ((size_t)bc * NH + h) * (HD * DSTATE);
#pragma unroll
    for (int hs = 0; hs < 2; hs++) {
#pragma unroll
      for (int ct = 0; ct < 4; ct++) {
        int p = ct * 16 + r15;
        int n0 = hs * 64 + wm + quad * 4;
        bf16x4 r;
#pragma unroll
        for (int i = 0; i < 4; i++) r[i] = (__bf16)accs[hs][ct][i];
        *(bf16x4*)(statesT + sbase + (size_t)p * DSTATE + n0) = r;
      }
    }
    __syncthreads();   // before next head overwrites xdT/xsT
  }
}

// ---------------- K5: inter-chunk scan (in-place, 4 elems/thread, bf16x4) --
// Round-5 validated (+5 µs vs narrow): 8B/lane + manual next-chunk prefetch.
__global__ __launch_bounds__(256) void k_scan(__hip_bfloat16* __restrict__ states,
    const float* __restrict__ echunk) {
  int idx = blockIdx.x * 256 + threadIdx.x;   // 131072
  int inner = (idx & 2047) * 4;    // p*128+n, quad-aligned
  int h = (idx >> 11) & 31;
  int b = idx >> 16;
  float run0 = 0.f, run1 = 0.f, run2 = 0.f, run3 = 0.f;
  size_t off = ((size_t)(b * NCH) * NH + h) * 8192 + inner;
  const size_t cstride = (size_t)NH * 8192;
  bf16x4 v = *(bf16x4*)(states + off);
  for (int c = 0; c < NCH; c++) {
    bf16x4 vn;
    if (c + 1 < NCH) vn = *(bf16x4*)(states + off + cstride);   // prefetch
    float e = echunk[(b * NCH + c) * NH + h];
    bf16x4 w = {(__bf16)run0, (__bf16)run1, (__bf16)run2, (__bf16)run3};
    *(bf16x4*)(states + off) = w;
    run0 = run0 * e + (float)v[0];
    run1 = run1 * e + (float)v[1];
    run2 = run2 * e + (float)v[2];
    run3 = run3 * e + (float)v[3];
    v = vn;
    off += cstride;
  }
}

// ---------------- K6: y += exp(acum)*(C.S_in^T), 4 heads/block, C reused ---
__global__ __launch_bounds__(256) void k_ssd2(
    const __hip_bfloat16* __restrict__ statesT, const __hip_bfloat16* __restrict__ Cm,
    const float* __restrict__ acum, __hip_bfloat16* __restrict__ y) {
  __shared__ __attribute__((aligned(16))) __hip_bfloat16 Cb[64 * 128];  // [l][n] swz
  __shared__ __attribute__((aligned(16))) __hip_bfloat16 Sb[64 * 128];  // [p][n] swz
  __shared__ __attribute__((aligned(16))) __hip_bfloat16 Yt[64 * 64];   // [l][p]
  __shared__ float aout[4 * 64];
  int bc = blockIdx.x, h0 = blockIdx.y * 4;
  int base = bc * CH;
  int tid = threadIdx.x, wid = tid >> 6, lane = tid & 63;
  int r15 = lane & 15, quad = lane >> 4;
  int wm = wid * 16;
  int srow = lane >> 4, g = lane & 15;

  aout[tid] = __expf(acum[(base + (tid & 63)) * NH + h0 + (tid >> 6)]);
  // stage Cb once (reused for all 4 heads)
  for (int c = 0; c < 4; c++) {
    int R0 = wid * 16 + c * 4;
    int r = R0 + srow;
    int gs = g ^ (r & 7);
    gload_lds16(Cm + (size_t)(base + r) * DSTATE + gs * 8, &Cb[R0 * DSTATE]);
  }

  for (int hh = 0; hh < 4; hh++) {
    int h = h0 + hh;
    size_t sbase = ((size_t)bc * NH + h) * (HD * DSTATE);
    // stage Sb + Yt for this head
    for (int c = 0; c < 4; c++) {
      int R0 = wid * 16 + c * 4;
      int r = R0 + srow;
      int gs = g ^ (r & 7);
      gload_lds16(statesT + sbase + (size_t)r * DSTATE + gs * 8, &Sb[R0 * DSTATE]);
    }
    for (int c = 0; c < 2; c++) {
      int R0 = wid * 16 + c * 8;
      int r = R0 + (lane >> 3);
      gload_lds16(y + (size_t)(base + r) * DIN + h * HD + (lane & 7) * 8, &Yt[R0 * 64]);
    }
    __syncthreads();

    f32x4 acc[4];
    f32x4 zz = {0.f, 0.f, 0.f, 0.f};
    for (int ct = 0; ct < 4; ct++) acc[ct] = zz;
#pragma unroll
    for (int ks = 0; ks < 4; ks++) {
      int arow = wm + r15;
      bf16x8 af = *(const bf16x8*)&Cb[arow * 128 + (((ks * 4 + quad) ^ (r15 & 7)) << 3)];
#pragma unroll
      for (int ct = 0; ct < 4; ct++) {
        int brow = ct * 16 + r15;
        bf16x8 bfr = *(const bf16x8*)&Sb[brow * 128 + (((ks * 4 + quad) ^ (r15 & 7)) << 3)];
        acc[ct] = __builtin_amdgcn_mfma_f32_16x16x32_bf16(af, bfr, acc[ct], 0, 0, 0);
      }
    }
#pragma unroll
    for (int ct = 0; ct < 4; ct++) {
      int p = ct * 16 + r15;
#pragma unroll
      for (int i = 0; i < 4; i++) {
        int l = wm + quad * 4 + i;
        float v = __bfloat162float(Yt[l * 64 + p]) + aout[hh * 64 + l] * acc[ct][i];
        y[(size_t)(base + l) * DIN + h * HD + p] = __float2bfloat16(v);
      }
    }
    __syncthreads();   // before next head's staging overwrites Sb/Yt
  }
}

extern "C" void kernel_launch(void* const* d_in, const int* in_sizes, int n_in,
                              void* d_out, int out_size, void* d_ws, size_t ws_size,
                              hipStream_t stream) {
  const float* x       = (const float*)d_in[0];
  const float* in_w    = (const float*)d_in[1];
  const float* conv_w  = (const float*)d_in[2];
  const float* conv_b  = (const float*)d_in[3];
  const float* dt_bias = (const float*)d_in[4];
  const float* A_log   = (const float*)d_in[5];
  const float* Dp      = (const float*)d_in[6];
  const float* out_w   = (const float*)d_in[7];
  float* out = (float*)d_out;

  char* cur = (char*)d_ws;
  auto alloc = [&](size_t bytes) {
    char* p = cur;
    cur += (bytes + 255) & ~(size_t)255;
    return p;
  };
  __hip_bfloat16* xbc   = (__hip_bfloat16*)alloc((size_t)T_TOK * CONVD * 2);
  float* dtb            = (float*)alloc((size_t)T_TOK * NH * 4);
  float* acum           = (float*)alloc((size_t)T_TOK * NH * 4);
  float* echunk         = (float*)alloc((size_t)NBC * NH * 4);
  __hip_bfloat16* xh    = (__hip_bfloat16*)alloc((size_t)T_TOK * DIN * 2);
  __hip_bfloat16* Bm    = (__hip_bfloat16*)alloc((size_t)T_TOK * DSTATE * 2);
  __hip_bfloat16* Cm    = (__hip_bfloat16*)alloc((size_t)T_TOK * DSTATE * 2);
  __hip_bfloat16* ybuf  = (__hip_bfloat16*)alloc((size_t)T_TOK * DIN * 2);
  __hip_bfloat16* states= (__hip_bfloat16*)alloc((size_t)NBC * NH * HD * DSTATE * 2);
  __hip_bfloat16* wib   = (__hip_bfloat16*)alloc((size_t)NPAD * DM * 2);
  __hip_bfloat16* wob   = (__hip_bfloat16*)alloc((size_t)DIN * DM * 2);
  __hip_bfloat16* xb    = states;   // alias: xb dead before k_ssd1 writes states

  k_pre    <<<dim3(9312), 256, 0, stream>>>(x, xb, in_w, wib, out_w, wob);
  k_gemmp<DM, true, NPAD / 128><<<dim3((NPAD / 128) * (T_TOK / 128)), 256, 0, stream>>>(
      xb, wib, nullptr, xbc, dtb, dt_bias, 0);
  k_conv   <<<dim3(3, T_TOK), 256, 0, stream>>>(xbc, conv_w, conv_b, xh, Bm, Cm);
  k_ssd1   <<<dim3(NBC, 4),   256, 0, stream>>>(xh, Bm, Cm, dtb, A_log, Dp, ybuf, states, acum, echunk);
  k_scan   <<<dim3(512),      256, 0, stream>>>(states, echunk);
  k_ssd2   <<<dim3(NBC, 8),   256, 0, stream>>>(states, Cm, acum, ybuf);
  k_gemmp<DIN, false, DM / 128><<<dim3((DM / 128) * (T_TOK / 128)), 256, 0, stream>>>(
      ybuf, wob, out, nullptr, nullptr, nullptr, DM);
}

// Round 9
// 318.760 us; speedup vs baseline: 1.0802x; 1.0552x over previous
//
#include <hip/hip_runtime.h>
#include <hip/hip_bf16.h>
#include <math.h>
#include <stdint.h>

#define T_TOK 8192      // b*l
#define L_SEQ 4096
#define DM    1024
#define DIN   2048
#define DSTATE 128
#define NH    32
#define HD    64
#define CH    64        // chunk length
#define NCH   64        // chunks per batch
#define NBC   128       // B * NCH
#define CONVD 2304
#define NPROJ 2336      // columns of in_proj we actually need (z gate unused)
#define NPAD  2432      // NPROJ padded to multiple of 128
#define PROJ_OFF 2048
#define DPROJ 4384

typedef __bf16 bf16x8 __attribute__((ext_vector_type(8)));
typedef __bf16 bf16x4 __attribute__((ext_vector_type(4)));
typedef __bf16 bf16x2 __attribute__((ext_vector_type(2)));
typedef float f32x4 __attribute__((ext_vector_type(4)));

__device__ __forceinline__ void gload_lds16(const void* g, void* l) {
  __builtin_amdgcn_global_load_lds(
      (const __attribute__((address_space(1))) void*)(uintptr_t)g,
      (__attribute__((address_space(3))) void*)(uintptr_t)l, 16, 0, 0);
}

#define SCHEDB() __builtin_amdgcn_sched_barrier(0)
#define BARx()   __builtin_amdgcn_s_barrier()
#define LGKM0() do { asm volatile("s_waitcnt lgkmcnt(0)" ::: "memory"); SCHEDB(); } while (0)
#define VMC(N)  do { asm volatile("s_waitcnt vmcnt(" #N ")" ::: "memory"); SCHEDB(); } while (0)

// ---------------- K0: fused preprocessing: cast x + transpose both weights --
__global__ __launch_bounds__(256) void k_pre(const float* __restrict__ x,
    __hip_bfloat16* __restrict__ xb, const float* __restrict__ in_w,
    __hip_bfloat16* __restrict__ wib, const float* __restrict__ out_w,
    __hip_bfloat16* __restrict__ wob) {
  __shared__ float s[64][65];
  int bid = blockIdx.x;
  if (bid < 8192) {                       // cast x -> bf16
    int i = (bid * 256 + threadIdx.x) * 4;
    float4 v = *(const float4*)(x + i);
    bf16x4 r;
    r[0] = (__bf16)v.x; r[1] = (__bf16)v.y; r[2] = (__bf16)v.z; r[3] = (__bf16)v.w;
    *(bf16x4*)(xb + i) = r;
    return;
  }
  const float* w; __hip_bfloat16* wt;
  int K, ldsrc, colOff, ncols, kx, ny;
  if (bid < 8800) {                       // in_proj weight transpose
    int b2 = bid - 8192; kx = b2 & 15; ny = b2 >> 4;
    w = in_w; wt = wib; K = DM; ldsrc = DPROJ; colOff = PROJ_OFF; ncols = NPROJ;
  } else {                                // out_proj weight transpose
    int b3 = bid - 8800; kx = b3 & 31; ny = b3 >> 5;
    w = out_w; wt = wob; K = DIN; ldsrc = DM; colOff = 0; ncols = DM;
  }
  int k0 = kx * 64, n0 = ny * 64;
  int c = threadIdx.x & 63, r0 = threadIdx.x >> 6;
  for (int i = 0; i < 16; i++) {
    int r = r0 + 4 * i;
    int ng = n0 + c;
    s[r][c] = (ng < ncols) ? w[(size_t)(k0 + r) * ldsrc + colOff + ng] : 0.f;
  }
  __syncthreads();
  for (int i = 0; i < 16; i++) {
    int a = r0 + 4 * i;
    wt[(size_t)(n0 + a) * K + k0 + c] = __float2bfloat16(s[c][a]);
  }
}

// ---------------- MFMA GEMM (round-4 proven structure, 67 µs) --------------
// reads -> lgkm0 -> barrier -> stage(it+2) -> MFMA -> counted VMC -> barrier.
// vmcnt ledger (8 loads/stage, in-order):
//   steady (it < nIter-2): outstanding 16 -> VMC(8) drains stage(it-1)
//     which feeds iter it+1; this iter's 8 stay in flight.
//   it == nIter-2: stage skipped -> outstanding 8 = last buffer's loads
//     -> VMC(0) full drain.  it == nIter-1: nothing outstanding.
// (Round-5 A/B: other orderings regressed 67->75/78 µs. Local optimum of the
//  128² dbuf structure; do not re-perturb without new counter evidence.)
template <int KDIM, bool SPLIT, int NTN>
__global__ __launch_bounds__(256) void k_gemmp(
    const __hip_bfloat16* __restrict__ A, const __hip_bfloat16* __restrict__ Bt,
    float* __restrict__ C, __hip_bfloat16* __restrict__ Cb16,
    float* __restrict__ dtb, const float* __restrict__ dt_bias, int NLD) {
  __shared__ __attribute__((aligned(16))) __hip_bfloat16 sA[2][128 * 64];
  __shared__ __attribute__((aligned(16))) __hip_bfloat16 sB[2][128 * 64];
  int tid = threadIdx.x;
  int wid = tid >> 6, lane = tid & 63;
  // T1: bijective XCD swizzle (gridDim.x divisible by 8)
  int f = blockIdx.x;
  int wg = (f & 7) * ((int)gridDim.x >> 3) + (f >> 3);
  int t0 = (wg / NTN) * 128, n0 = (wg % NTN) * 128;
  int wm = (wid >> 1) * 64, wn = (wid & 1) * 64;
  int r15 = lane & 15, quad = lane >> 4;
  int srow = lane >> 3;
  int kcs = lane & 7;

  f32x4 acc[4][4];
  f32x4 zz = {0.f, 0.f, 0.f, 0.f};
  for (int ni = 0; ni < 4; ni++)
    for (int ti = 0; ti < 4; ti++) acc[ni][ti] = zz;

  const __hip_bfloat16* Abase = A + (size_t)t0 * KDIM;
  const __hip_bfloat16* Bbase = Bt + (size_t)n0 * KDIM;

  auto stage = [&](int bb, int k0) {
#pragma unroll
    for (int c = 0; c < 4; c++) {
      int R0 = (wid * 4 + c) * 8;
      int row = R0 + srow;
      int kcg = kcs ^ (row & 7);
      gload_lds16(Abase + (size_t)row * KDIM + k0 + kcg * 8, &sA[bb][R0 * 64]);
      gload_lds16(Bbase + (size_t)row * KDIM + k0 + kcg * 8, &sB[bb][R0 * 64]);
    }
  };

  // prologue: two tiles in flight; wait only for the first
  stage(0, 0);
  stage(1, 64);
  VMC(8);
  BARx(); SCHEDB();

  const int nIter = KDIM / 64;
  for (int it = 0; it < nIter; ++it) {
    const int bb = it & 1;
    // 1) whole current tile -> registers
    bf16x8 wf[4][2], xf[4][2];
#pragma unroll
    for (int s = 0; s < 2; s++) {
      int sw = ((s << 2) | quad) ^ (r15 & 7);
#pragma unroll
      for (int ni = 0; ni < 4; ni++)
        wf[ni][s] = *reinterpret_cast<const bf16x8*>(&sB[bb][(wn + ni * 16 + r15) * 64 + sw * 8]);
#pragma unroll
      for (int ti = 0; ti < 4; ti++)
        xf[ti][s] = *reinterpret_cast<const bf16x8*>(&sA[bb][(wm + ti * 16 + r15) * 64 + sw * 8]);
    }
    LGKM0();            // own ds_reads complete
    BARx(); SCHEDB();   // all waves' reads complete -> cur buffer reusable
    // 2) refill cur buffer for iteration it+2 (async, ~2-iter lead)
    if (it + 2 < nIter) stage(bb, (it + 2) * 64);
    // 3) compute from registers
#pragma unroll
    for (int s = 0; s < 2; s++)
#pragma unroll
      for (int ni = 0; ni < 4; ni++)
#pragma unroll
        for (int ti = 0; ti < 4; ti++)
          acc[ni][ti] = __builtin_amdgcn_mfma_f32_16x16x32_bf16(wf[ni][s], xf[ti][s], acc[ni][ti], 0, 0, 0);
    // 4) guard the next buffer's staging loads (see ledger above)
    if (it < nIter - 2) {
      VMC(8);
      BARx(); SCHEDB();
    } else if (it == nIter - 2) {
      VMC(0);                      // last buffer's loads: full drain
      BARx(); SCHEDB();
    }
    // it == nIter-1: fall through to epilogue, nothing outstanding
  }

  // epilogue: D[n = quad*4+i][t = r15], vector stores over n
#pragma unroll
  for (int ni = 0; ni < 4; ni++) {
    int n = n0 + wn + ni * 16 + quad * 4;
#pragma unroll
    for (int ti = 0; ti < 4; ti++) {
      int t = t0 + wm + ti * 16 + r15;
      f32x4 v = acc[ni][ti];
      if (SPLIT) {
        if (n < CONVD) {
          bf16x4 r;
#pragma unroll
          for (int i = 0; i < 4; i++) r[i] = (__bf16)v[i];
          *(bf16x4*)(Cb16 + (size_t)t * CONVD + n) = r;
        } else if (n < NPROJ) {     // [CONVD, NPROJ) — 4-aligned boundary
#pragma unroll
          for (int i = 0; i < 4; i++) {
            int h = n + i - CONVD;
            float z = v[i] + dt_bias[h];
            float sp = (z > 20.f) ? z : log1pf(__expf(z));
            dtb[t * NH + h] = sp;
          }
        }
        // n >= NPROJ: zero-padded columns, discarded
      } else {
        *(float4*)(C + (size_t)t * NLD + n) = *(float4*)&v;
      }
    }
  }
}

// ---------------- K2: depthwise causal conv(4) + bias + SiLU ----------------
// Round-9: 4 tokens per thread. Outputs t0..t0+3 need input rows t0-3..t0+3:
// 7 row-loads instead of 16, weight/bias loads amortized 4x, and each xbc
// row is fetched by exactly one block (was 4 -> up to 4x L2-miss traffic).
// 4096 % 4 == 0 so a token group never crosses a sequence boundary.
__global__ __launch_bounds__(256) void k_conv(const __hip_bfloat16* __restrict__ xbc,
    const float* __restrict__ cw, const float* __restrict__ cb,
    __hip_bfloat16* __restrict__ xh, __hip_bfloat16* __restrict__ Bm,
    __hip_bfloat16* __restrict__ Cm) {
  int pi = blockIdx.x * 256 + threadIdx.x;
  if (pi >= CONVD / 4) return;
  int ch = pi * 4;
  int t0 = blockIdx.y * 4;
  int l0 = t0 & (L_SEQ - 1);
  float4 cb4 = *(const float4*)(cb + ch);
  float4 w4[4];
#pragma unroll
  for (int j = 0; j < 4; j++) w4[j] = *(const float4*)(cw + j * CONVD + ch);
  // rows l0-3 .. l0+3 (7 rows); causal guard on sequence-local index
  bf16x4 rowv[7];
#pragma unroll
  for (int r = 0; r < 7; r++) {
    if (l0 - 3 + r >= 0)
      rowv[r] = *(const bf16x4*)(xbc + (size_t)(t0 - 3 + r) * CONVD + ch);
    else {
      bf16x4 z = {(__bf16)0.f, (__bf16)0.f, (__bf16)0.f, (__bf16)0.f};
      rowv[r] = z;
    }
  }
#pragma unroll
  for (int k = 0; k < 4; k++) {        // output token t0+k
    float acc[4] = {cb4.x, cb4.y, cb4.z, cb4.w};
#pragma unroll
    for (int j = 0; j < 4; j++) {
      bf16x4 v = rowv[k + j];
      acc[0] += (float)v[0] * w4[j].x;
      acc[1] += (float)v[1] * w4[j].y;
      acc[2] += (float)v[2] * w4[j].z;
      acc[3] += (float)v[3] * w4[j].w;
    }
    bf16x4 r;
#pragma unroll
    for (int i = 0; i < 4; i++) {
      float sv = acc[i] / (1.f + __expf(-acc[i]));
      r[i] = (__bf16)sv;
    }
    int t = t0 + k;
    if (ch < DIN)                 *(bf16x4*)(xh + (size_t)t * DIN + ch) = r;
    else if (ch < DIN + DSTATE)   *(bf16x4*)(Bm + (size_t)t * DSTATE + ch - DIN) = r;
    else                          *(bf16x4*)(Cm + (size_t)t * DSTATE + ch - DIN - DSTATE) = r;
  }
}

// ---------------- K4: fused SSD per (chunk, 8 heads), acum folded in --------
// All transposed LDS arrays use stride-64 XOR-granule layout: element (row, k)
// stored at row*64 + ((k>>3)^(row&7))*8 + (k&7). Store/read swizzles cancel.
// Round-9: exact round-4 body. Ledger: R6 operand-swap bundle −20 µs, R7 T14
// −14 µs, R8 S^T-swap-only −11 µs (bf16x4 stores are per-lane wide but
// inter-lane SCATTERED, 64×8B segments/instr; R4's "scalar" stores are
// wave-coalesced 4×32B segments/instr). Per-wave segment count is the
// metric, not per-lane width. Do not re-vectorize these epilogues.
__global__ __launch_bounds__(256) void k_ssd1(
    const __hip_bfloat16* __restrict__ xh, const __hip_bfloat16* __restrict__ Bm,
    const __hip_bfloat16* __restrict__ Cm, const float* __restrict__ dtb,
    const float* __restrict__ A_log, const float* __restrict__ Dp,
    __hip_bfloat16* __restrict__ ypart, __hip_bfloat16* __restrict__ statesT,
    float* __restrict__ acum_out, float* __restrict__ echunk) {
  __shared__ __attribute__((aligned(16))) char smem[32768 + 8192 + 6144];
  __hip_bfloat16* Cb  = (__hip_bfloat16*)smem;            // 64x128 swz (phase 1)
  __hip_bfloat16* Bb  = Cb + 64 * 128;                    // 64x128 swz (phase 1)
  __hip_bfloat16* BT  = (__hip_bfloat16*)smem;            // 128x64 [n][l] (phase 2, alias)
  __hip_bfloat16* xdT = BT + 128 * 64;                    // 64x64 [p][l] x*dt
  __hip_bfloat16* xsT = xdT + 64 * 64;                    // 64x64 [p][l] x*dt*dec
  __hip_bfloat16* P   = (__hip_bfloat16*)(smem + 32768);  // 64x64 [l][s]
  float* acvA = (float*)(smem + 32768 + 8192);            // [8][64]
  float* dtsA = acvA + 512;
  float* decA = dtsA + 512;

  int bc = blockIdx.x, h0 = blockIdx.y * 8;
  int base = bc * CH;
  int tid = threadIdx.x, wid = tid >> 6, lane = tid & 63;
  int r15 = lane & 15, quad = lane >> 4;
  int wm = wid * 16;
  f32x4 zz = {0.f, 0.f, 0.f, 0.f};

  // stage Cb/Bb via async gload (row-granule XOR swizzle on global side)
  {
    int srow = lane >> 4, g = lane & 15;
    for (int c = 0; c < 4; c++) {
      int R0 = wid * 16 + c * 4;
      int r = R0 + srow;
      int gs = g ^ (r & 7);
      gload_lds16(Cm + (size_t)(base + r) * DSTATE + gs * 8, &Cb[R0 * DSTATE]);
      gload_lds16(Bm + (size_t)(base + r) * DSTATE + gs * 8, &Bb[R0 * DSTATE]);
    }
  }
  // preload dt (8 heads x 64 positions)
  for (int i = 0; i < 2; i++) {
    int idx = tid + 256 * i;
    int hh = idx >> 6, l = idx & 63;
    dtsA[hh * 64 + l] = dtb[(base + l) * NH + h0 + hh];
  }
  __syncthreads();
  // in-block cumsum of A*dt (one serial lane per head; 64 fp32 adds)
  if (tid < 8) {
    int h = h0 + tid;
    float a = -__expf(A_log[h]);
    float s = 0.f;
    for (int l = 0; l < CH; l++) {
      s += a * dtsA[tid * 64 + l];
      acvA[tid * 64 + l] = s;
    }
    echunk[bc * NH + h] = __expf(s);
  }
  __syncthreads();
  // dec + persist acum for k_ssd2
  for (int i = 0; i < 2; i++) {
    int idx = tid + 256 * i;
    int hh = idx >> 6, l = idx & 63;
    float a = acvA[hh * 64 + l];
    decA[hh * 64 + l] = __expf(acvA[hh * 64 + 63] - a);
    acum_out[(base + l) * NH + h0 + hh] = a;
  }

  // --- G = C.B^T once: wave strip rows wm..wm+15 x all 64 s (K=128)
  f32x4 accg[4];
  for (int ct = 0; ct < 4; ct++) accg[ct] = zz;
#pragma unroll
  for (int ks = 0; ks < 4; ks++) {
    int arow = wm + r15;
    bf16x8 af = *(const bf16x8*)&Cb[arow * 128 + (((ks * 4 + quad) ^ (r15 & 7)) << 3)];
#pragma unroll
    for (int ct = 0; ct < 4; ct++) {
      int brow = ct * 16 + r15;
      bf16x8 bfr = *(const bf16x8*)&Bb[brow * 128 + (((ks * 4 + quad) ^ (r15 & 7)) << 3)];
      accg[ct] = __builtin_amdgcn_mfma_f32_16x16x32_bf16(af, bfr, accg[ct], 0, 0, 0);
    }
  }
  __syncthreads();   // Cb/Bb dead; region reused below

  int l0 = (tid & 15) * 4;     // 4 consecutive l (same granule: l0%8 in {0,4})
  int q0 = tid >> 4;           // 0..15
  int go = l0 & 7;             // offset within granule
  int gl = l0 >> 3;            // true granule of l0

  for (int hh = 0; hh < 8; hh++) {
    int h = h0 + hh;
    if (hh == 0) {
      // build BT[n][l] once (head-independent, decay folded into xs)
      int n0 = q0 * 8;
      __bf16 tmp[8][4];
#pragma unroll
      for (int dl = 0; dl < 4; dl++) {
        bf16x8 bv = *(const bf16x8*)(Bm + (size_t)(base + l0 + dl) * DSTATE + n0);
#pragma unroll
        for (int dn = 0; dn < 8; dn++) tmp[dn][dl] = bv[dn];
      }
#pragma unroll
      for (int dn = 0; dn < 8; dn++) {
        int n = n0 + dn;
        bf16x4 pk = {tmp[dn][0], tmp[dn][1], tmp[dn][2], tmp[dn][3]};
        *(bf16x4*)&BT[n * 64 + ((gl ^ (n & 7)) << 3) + go] = pk;
      }
    }
    // build xdT (x*dt) and xsT (x*dt*dec) for this head: 4l x 4p per thread
    {
      int p0 = q0 * 4;
      __bf16 td[4][4], ts[4][4];
#pragma unroll
      for (int dl = 0; dl < 4; dl++) {
        int l = l0 + dl;
        bf16x4 xv = *(const bf16x4*)(xh + (size_t)(base + l) * DIN + h * HD + p0);
        float dt = dtsA[hh * 64 + l];
        float ds = dt * decA[hh * 64 + l];
#pragma unroll
        for (int dp = 0; dp < 4; dp++) {
          float xf = (float)xv[dp];
          td[dp][dl] = (__bf16)(xf * dt);
          ts[dp][dl] = (__bf16)(xf * ds);
        }
      }
#pragma unroll
      for (int dp = 0; dp < 4; dp++) {
        int p = p0 + dp;
        int off = p * 64 + ((gl ^ (p & 7)) << 3) + go;
        bf16x4 pd = {td[dp][0], td[dp][1], td[dp][2], td[dp][3]};
        bf16x4 ps = {ts[dp][0], ts[dp][1], ts[dp][2], ts[dp][3]};
        *(bf16x4*)&xdT[off] = pd;
        *(bf16x4*)&xsT[off] = ps;
      }
    }
    __syncthreads();

    // --- P = mask(G * decay) -> LDS (wave-private rows wm..wm+15)
#pragma unroll
    for (int ct = 0; ct < 4; ct++) {
      int s = ct * 16 + r15;
      float as = acvA[hh * 64 + s];
#pragma unroll
      for (int i = 0; i < 4; i++) {
        int l = wm + quad * 4 + i;
        float pv = (s <= l) ? accg[ct][i] * __expf(acvA[hh * 64 + l] - as) : 0.f;
        P[l * 64 + (((s >> 3) ^ (l & 7)) << 3) + (s & 7)] = __float2bfloat16(pv);
      }
    }
    // --- Y_diag = P.xd (K=64) + xh*D
    f32x4 accy[4];
    for (int ct = 0; ct < 4; ct++) accy[ct] = zz;
#pragma unroll
    for (int ks = 0; ks < 2; ks++) {
      int arow = wm + r15;
      bf16x8 af = *(const bf16x8*)&P[arow * 64 + (((ks * 4 + quad) ^ (r15 & 7)) << 3)];
#pragma unroll
      for (int ct = 0; ct < 4; ct++) {
        int brow = ct * 16 + r15;
        bf16x8 bfr = *(const bf16x8*)&xdT[brow * 64 + (((ks * 4 + quad) ^ (r15 & 7)) << 3)];
        accy[ct] = __builtin_amdgcn_mfma_f32_16x16x32_bf16(af, bfr, accy[ct], 0, 0, 0);
      }
    }
    float Dh = Dp[h];
#pragma unroll
    for (int ct = 0; ct < 4; ct++) {
      int p = ct * 16 + r15;
#pragma unroll
      for (int i = 0; i < 4; i++) {
        int l = wm + quad * 4 + i;
        float xv = __bfloat162float(xh[(size_t)(base + l) * DIN + h * HD + p]);
        ypart[(size_t)(base + l) * DIN + h * HD + p] = __float2bfloat16(accy[ct][i] + xv * Dh);
      }
    }
    // --- S^T[p][n] = sum_l xs[l][p] * B[l][n]  (K=64, wave strip over p)
    f32x4 accs[8];
    for (int ct = 0; ct < 8; ct++) accs[ct] = zz;
#pragma unroll
    for (int ks = 0; ks < 2; ks++) {
      int arow = wm + r15;   // p row
      bf16x8 af = *(const bf16x8*)&xsT[arow * 64 + (((ks * 4 + quad) ^ (r15 & 7)) << 3)];
#pragma unroll
      for (int ct = 0; ct < 8; ct++) {
        int brow = ct * 16 + r15;   // n row
        bf16x8 bfr = *(const bf16x8*)&BT[brow * 64 + (((ks * 4 + quad) ^ (r15 & 7)) << 3)];
        accs[ct] = __builtin_amdgcn_mfma_f32_16x16x32_bf16(af, bfr, accs[ct], 0, 0, 0);
      }
    }
    size_t sbase = ((size_t)bc * NH + h) * (HD * DSTATE);
#pragma unroll
    for (int ct = 0; ct < 8; ct++) {
      int n = ct * 16 + r15;
#pragma unroll
      for (int i = 0; i < 4; i++) {
        int p = wm + quad * 4 + i;
        statesT[sbase + (size_t)p * DSTATE + n] = __float2bfloat16(accs[ct][i]);
      }
    }
    __syncthreads();   // before next head overwrites xdT/xsT
  }
}

// ---------------- K5: inter-chunk scan (in-place, 4 elems/thread, bf16x4) --
// Round-5 validated (−5 µs vs narrow): 8B/lane + manual next-chunk prefetch.
__global__ __launch_bounds__(256) void k_scan(__hip_bfloat16* __restrict__ states,
    const float* __restrict__ echunk) {
  int idx = blockIdx.x * 256 + threadIdx.x;   // 131072
  int inner = (idx & 2047) * 4;    // p*128+n, quad-aligned
  int h = (idx >> 11) & 31;
  int b = idx >> 16;
  float run0 = 0.f, run1 = 0.f, run2 = 0.f, run3 = 0.f;
  size_t off = ((size_t)(b * NCH) * NH + h) * 8192 + inner;
  const size_t cstride = (size_t)NH * 8192;
  bf16x4 v = *(bf16x4*)(states + off);
  for (int c = 0; c < NCH; c++) {
    bf16x4 vn;
    if (c + 1 < NCH) vn = *(bf16x4*)(states + off + cstride);   // prefetch
    float e = echunk[(b * NCH + c) * NH + h];
    bf16x4 w = {(__bf16)run0, (__bf16)run1, (__bf16)run2, (__bf16)run3};
    *(bf16x4*)(states + off) = w;
    run0 = run0 * e + (float)v[0];
    run1 = run1 * e + (float)v[1];
    run2 = run2 * e + (float)v[2];
    run3 = run3 * e + (float)v[3];
    v = vn;
    off += cstride;
  }
}

// ---------------- K6: y += exp(acum)*(C.S_in^T), 4 heads/block, C reused ---
__global__ __launch_bounds__(256) void k_ssd2(
    const __hip_bfloat16* __restrict__ statesT, const __hip_bfloat16* __restrict__ Cm,
    const float* __restrict__ acum, __hip_bfloat16* __restrict__ y) {
  __shared__ __attribute__((aligned(16))) __hip_bfloat16 Cb[64 * 128];  // [l][n] swz
  __shared__ __attribute__((aligned(16))) __hip_bfloat16 Sb[64 * 128];  // [p][n] swz
  __shared__ __attribute__((aligned(16))) __hip_bfloat16 Yt[64 * 64];   // [l][p]
  __shared__ float aout[4 * 64];
  int bc = blockIdx.x, h0 = blockIdx.y * 4;
  int base = bc * CH;
  int tid = threadIdx.x, wid = tid >> 6, lane = tid & 63;
  int r15 = lane & 15, quad = lane >> 4;
  int wm = wid * 16;
  int srow = lane >> 4, g = lane & 15;

  aout[tid] = __expf(acum[(base + (tid & 63)) * NH + h0 + (tid >> 6)]);
  // stage Cb once (reused for all 4 heads)
  for (int c = 0; c < 4; c++) {
    int R0 = wid * 16 + c * 4;
    int r = R0 + srow;
    int gs = g ^ (r & 7);
    gload_lds16(Cm + (size_t)(base + r) * DSTATE + gs * 8, &Cb[R0 * DSTATE]);
  }

  for (int hh = 0; hh < 4; hh++) {
    int h = h0 + hh;
    size_t sbase = ((size_t)bc * NH + h) * (HD * DSTATE);
    // stage Sb + Yt for this head
    for (int c = 0; c < 4; c++) {
      int R0 = wid * 16 + c * 4;
      int r = R0 + srow;
      int gs = g ^ (r & 7);
      gload_lds16(statesT + sbase + (size_t)r * DSTATE + gs * 8, &Sb[R0 * DSTATE]);
    }
    for (int c = 0; c < 2; c++) {
      int R0 = wid * 16 + c * 8;
      int r = R0 + (lane >> 3);
      gload_lds16(y + (size_t)(base + r) * DIN + h * HD + (lane & 7) * 8, &Yt[R0 * 64]);
    }
    __syncthreads();

    f32x4 acc[4];
    f32x4 zz = {0.f, 0.f, 0.f, 0.f};
    for (int ct = 0; ct < 4; ct++) acc[ct] = zz;
#pragma unroll
    for (int ks = 0; ks < 4; ks++) {
      int arow = wm + r15;
      bf16x8 af = *(const bf16x8*)&Cb[arow * 128 + (((ks * 4 + quad) ^ (r15 & 7)) << 3)];
#pragma unroll
      for (int ct = 0; ct < 4; ct++) {
        int brow = ct * 16 + r15;
        bf16x8 bfr = *(const bf16x8*)&Sb[brow * 128 + (((ks * 4 + quad) ^ (r15 & 7)) << 3)];
        acc[ct] = __builtin_amdgcn_mfma_f32_16x16x32_bf16(af, bfr, acc[ct], 0, 0, 0);
      }
    }
#pragma unroll
    for (int ct = 0; ct < 4; ct++) {
      int p = ct * 16 + r15;
#pragma unroll
      for (int i = 0; i < 4; i++) {
        int l = wm + quad * 4 + i;
        float v = __bfloat162float(Yt[l * 64 + p]) + aout[hh * 64 + l] * acc[ct][i];
        y[(size_t)(base + l) * DIN + h * HD + p] = __float2bfloat16(v);
      }
    }
    __syncthreads();   // before next head's staging overwrites Sb/Yt
  }
}

extern "C" void kernel_launch(void* const* d_in, const int* in_sizes, int n_in,
                              void* d_out, int out_size, void* d_ws, size_t ws_size,
                              hipStream_t stream) {
  const float* x       = (const float*)d_in[0];
  const float* in_w    = (const float*)d_in[1];
  const float* conv_w  = (const float*)d_in[2];
  const float* conv_b  = (const float*)d_in[3];
  const float* dt_bias = (const float*)d_in[4];
  const float* A_log   = (const float*)d_in[5];
  const float* Dp      = (const float*)d_in[6];
  const float* out_w   = (const float*)d_in[7];
  float* out = (float*)d_out;

  char* cur = (char*)d_ws;
  auto alloc = [&](size_t bytes) {
    char* p = cur;
    cur += (bytes + 255) & ~(size_t)255;
    return p;
  };
  __hip_bfloat16* xbc   = (__hip_bfloat16*)alloc((size_t)T_TOK * CONVD * 2);
  float* dtb            = (float*)alloc((size_t)T_TOK * NH * 4);
  float* acum           = (float*)alloc((size_t)T_TOK * NH * 4);
  float* echunk         = (float*)alloc((size_t)NBC * NH * 4);
  __hip_bfloat16* xh    = (__hip_bfloat16*)alloc((size_t)T_TOK * DIN * 2);
  __hip_bfloat16* Bm    = (__hip_bfloat16*)alloc((size_t)T_TOK * DSTATE * 2);
  __hip_bfloat16* Cm    = (__hip_bfloat16*)alloc((size_t)T_TOK * DSTATE * 2);
  __hip_bfloat16* ybuf  = (__hip_bfloat16*)alloc((size_t)T_TOK * DIN * 2);
  __hip_bfloat16* states= (__hip_bfloat16*)alloc((size_t)NBC * NH * HD * DSTATE * 2);
  __hip_bfloat16* wib   = (__hip_bfloat16*)alloc((size_t)NPAD * DM * 2);
  __hip_bfloat16* wob   = (__hip_bfloat16*)alloc((size_t)DIN * DM * 2);
  __hip_bfloat16* xb    = states;   // alias: xb dead before k_ssd1 writes states

  k_pre    <<<dim3(9312), 256, 0, stream>>>(x, xb, in_w, wib, out_w, wob);
  k_gemmp<DM, true, NPAD / 128><<<dim3((NPAD / 128) * (T_TOK / 128)), 256, 0, stream>>>(
      xb, wib, nullptr, xbc, dtb, dt_bias, 0);
  k_conv   <<<dim3(3, T_TOK / 4), 256, 0, stream>>>(xbc, conv_w, conv_b, xh, Bm, Cm);
  k_ssd1   <<<dim3(NBC, 4),   256, 0, stream>>>(xh, Bm, Cm, dtb, A_log, Dp, ybuf, states, acum, echunk);
  k_scan   <<<dim3(512),      256, 0, stream>>>(states, echunk);
  k_ssd2   <<<dim3(NBC, 8),   256, 0, stream>>>(states, Cm, acum, ybuf);
  k_gemmp<DIN, false, DM / 128><<<dim3((DM / 128) * (T_TOK / 128)), 256, 0, stream>>>(
      ybuf, wob, out, nullptr, nullptr, nullptr, DM);
}